// Round 5
// baseline (701.250 us; speedup 1.0000x reference)
//
#include <hip/hip_runtime.h>
#include <hip/hip_bf16.h>
#include <cstdio>

typedef unsigned short u16;
typedef __bf16 bf16x8 __attribute__((ext_vector_type(8)));
typedef float  floatx4 __attribute__((ext_vector_type(4)));

// ---------- scalar helpers ----------
__device__ __forceinline__ float bf2f(u16 u) {
  union { unsigned int i; float f; } v; v.i = ((unsigned int)u) << 16; return v.f;
}
__device__ __forceinline__ u16 f2bf(float f) {
  union { float f; unsigned int i; } v; v.f = f;
  unsigned int x = v.i;
  return (u16)((x + 0x7fffu + ((x >> 16) & 1u)) >> 16);   // RNE
}
__device__ __forceinline__ unsigned int f2bf_pk(float a, float b) {   // [lo=a, hi=b]
  __hip_bfloat162 h = __float22bfloat162_rn(make_float2(a, b));
  union { __hip_bfloat162 h; unsigned int u; } v; v.h = h; return v.u;
}
// fast gates: v_rcp (~1 ulp) + native exp — no IEEE div
__device__ __forceinline__ float sigmoidf_(float x) {
  return __builtin_amdgcn_rcpf(1.f + __expf(-x));
}
__device__ __forceinline__ float tanhf_(float x) {
  return fmaf(-2.f, __builtin_amdgcn_rcpf(1.f + __expf(2.f * x)), 1.f);
}

// LDS swizzle, 128-elem rows, 16B chunks: chunk' = chunk ^ (row&15)
__device__ __forceinline__ int swz128(int row, int c16) {
  return row * 128 + ((c16 ^ (row & 15)) << 3);
}
// element-level access into swizzled rows
__device__ __forceinline__ int swze(int row, int col) {
  return row * 128 + (((((col >> 3)) ^ (row & 15)) << 3) | (col & 7));
}

// ============ proj_e: Ep[v][col][4] = {i,u,o,f} pre-acts + biases (gate-interleaved) ============
__global__ __launch_bounds__(256, 2) void proj_e(
    const float* __restrict__ emb, const u16* __restrict__ WT,
    const float* __restrict__ bsum, u16* __restrict__ Ep)
{
  __shared__ __align__(16) u16 ldsA[128 * 128];
  const int tid = threadIdx.x;
  const long m0 = (long)blockIdx.x * 128;
  {
    const int r = tid >> 1, half = tid & 1;
    long row = m0 + r; if (row > 49999) row = 49999;
    const float* src = emb + row * 128 + half * 64;
#pragma unroll
    for (int i = 0; i < 8; i++) {
      float4 v0 = *reinterpret_cast<const float4*>(src + i * 8);
      float4 v1 = *reinterpret_cast<const float4*>(src + i * 8 + 4);
      unsigned int ov[4] = { f2bf_pk(v0.x, v0.y), f2bf_pk(v0.z, v0.w),
                             f2bf_pk(v1.x, v1.y), f2bf_pk(v1.z, v1.w) };
      *reinterpret_cast<uint4*>(&ldsA[swz128(r, half * 8 + i)]) =
          *reinterpret_cast<const uint4*>(ov);
    }
  }
  __syncthreads();
  const int lane = tid & 63, w = tid >> 6, l16 = lane & 15, quad = lane >> 4;
#pragma unroll
  for (int half = 0; half < 2; half++) {
    const int col = w * 32 + half * 16 + l16;
    bf16x8 bI[4], bU[4], bO[4], bF[4];
#pragma unroll
    for (int ks = 0; ks < 4; ks++) {
      const size_t o_ = ks * 32 + quad * 8;
      bI[ks] = *reinterpret_cast<const bf16x8*>(WT + (size_t)(0   + col) * 128 + o_);
      bU[ks] = *reinterpret_cast<const bf16x8*>(WT + (size_t)(128 + col) * 128 + o_);
      bO[ks] = *reinterpret_cast<const bf16x8*>(WT + (size_t)(256 + col) * 128 + o_);
      bF[ks] = *reinterpret_cast<const bf16x8*>(WT + (size_t)(384 + col) * 128 + o_);
    }
    const float bi = bsum[col], bu = bsum[128 + col], bo = bsum[256 + col], bf = bsum[384 + col];
#pragma unroll
    for (int i = 0; i < 8; i++) {
      floatx4 aI = {0.f,0.f,0.f,0.f}, aU = {0.f,0.f,0.f,0.f};
      floatx4 aO = {0.f,0.f,0.f,0.f}, aF = {0.f,0.f,0.f,0.f};
#pragma unroll
      for (int ks = 0; ks < 4; ks++) {
        bf16x8 a = *reinterpret_cast<const bf16x8*>(&ldsA[swz128(i * 16 + l16, ks * 4 + quad)]);
        aI = __builtin_amdgcn_mfma_f32_16x16x32_bf16(a, bI[ks], aI, 0, 0, 0);
        aU = __builtin_amdgcn_mfma_f32_16x16x32_bf16(a, bU[ks], aU, 0, 0, 0);
        aO = __builtin_amdgcn_mfma_f32_16x16x32_bf16(a, bO[ks], aO, 0, 0, 0);
        aF = __builtin_amdgcn_mfma_f32_16x16x32_bf16(a, bF[ks], aF, 0, 0, 0);
      }
#pragma unroll
      for (int r2 = 0; r2 < 4; r2++) {
        const long row = m0 + i * 16 + quad * 4 + r2;
        if (row < 50000) {
          u16 ov[4] = { f2bf(aI[r2] + bi), f2bf(aU[r2] + bu),
                        f2bf(aO[r2] + bo), f2bf(aF[r2] + bf) };
          *reinterpret_cast<ushort4*>(Ep + row * 512 + col * 4) =
              *reinterpret_cast<const ushort4*>(ov);
        }
      }
    }
  }
}

// ============ proj_hc: fused leaf activations + h-side projection ============
// Staging: Ep[v] -> leaf h (LDS, swizzled) and leaf c -> Cl[v] (global).
// MFMA:    Gh[v][col][4] = {i,u,o,f} h-side pre-acts = Hleaf[v] @ W_*h (no bias).
__global__ __launch_bounds__(256, 2) void proj_hc(
    const u16* __restrict__ Ep,
    const u16* __restrict__ BihT, const u16* __restrict__ BuhT,
    const u16* __restrict__ BohT, const u16* __restrict__ BfT,
    u16* __restrict__ Cl, u16* __restrict__ Gh)
{
  __shared__ __align__(16) u16 ldsA[128 * 128];
  const int tid = threadIdx.x;
  const long m0 = (long)blockIdx.x * 128;
  {
    const int r = tid >> 1, half = tid & 1;
    long row = m0 + r;
    const bool ok = (row < 50000); if (!ok) row = 49999;
    const u16* src = Ep + row * 512 + half * 256;
#pragma unroll
    for (int i = 0; i < 8; i++) {
      uint4 v[4];
#pragma unroll
      for (int k = 0; k < 4; k++)
        v[k] = *reinterpret_cast<const uint4*>(src + i * 32 + k * 8);
      unsigned int hp[4], cp[4];
#pragma unroll
      for (int k = 0; k < 4; k++) {      // each uint4 = 2 cols x {i,u,o,f}
        const u16* p = reinterpret_cast<const u16*>(&v[k]);
        float c0 = sigmoidf_(bf2f(p[0])) * tanhf_(bf2f(p[1]));
        float c1 = sigmoidf_(bf2f(p[4])) * tanhf_(bf2f(p[5]));
        float h0 = sigmoidf_(bf2f(p[2])) * tanhf_(c0);
        float h1 = sigmoidf_(bf2f(p[6])) * tanhf_(c1);
        cp[k] = f2bf_pk(c0, c1);
        hp[k] = f2bf_pk(h0, h1);
      }
      *reinterpret_cast<uint4*>(&ldsA[swz128(r, half * 8 + i)]) =
          *reinterpret_cast<const uint4*>(hp);
      if (ok)
        *reinterpret_cast<uint4*>(Cl + row * 128 + half * 64 + i * 8) =
            *reinterpret_cast<const uint4*>(cp);
    }
  }
  __syncthreads();
  const int lane = tid & 63, w = tid >> 6, l16 = lane & 15, quad = lane >> 4;
#pragma unroll
  for (int half = 0; half < 2; half++) {
    const int col = w * 32 + half * 16 + l16;
    bf16x8 bI[4], bU[4], bO[4], bF[4];
#pragma unroll
    for (int ks = 0; ks < 4; ks++) {
      const size_t o_ = (size_t)col * 128 + ks * 32 + quad * 8;
      bI[ks] = *reinterpret_cast<const bf16x8*>(BihT + o_);
      bU[ks] = *reinterpret_cast<const bf16x8*>(BuhT + o_);
      bO[ks] = *reinterpret_cast<const bf16x8*>(BohT + o_);
      bF[ks] = *reinterpret_cast<const bf16x8*>(BfT  + o_);
    }
#pragma unroll
    for (int i = 0; i < 8; i++) {
      floatx4 aI = {0.f,0.f,0.f,0.f}, aU = {0.f,0.f,0.f,0.f};
      floatx4 aO = {0.f,0.f,0.f,0.f}, aF = {0.f,0.f,0.f,0.f};
#pragma unroll
      for (int ks = 0; ks < 4; ks++) {
        bf16x8 a = *reinterpret_cast<const bf16x8*>(&ldsA[swz128(i * 16 + l16, ks * 4 + quad)]);
        aI = __builtin_amdgcn_mfma_f32_16x16x32_bf16(a, bI[ks], aI, 0, 0, 0);
        aU = __builtin_amdgcn_mfma_f32_16x16x32_bf16(a, bU[ks], aU, 0, 0, 0);
        aO = __builtin_amdgcn_mfma_f32_16x16x32_bf16(a, bO[ks], aO, 0, 0, 0);
        aF = __builtin_amdgcn_mfma_f32_16x16x32_bf16(a, bF[ks], aF, 0, 0, 0);
      }
#pragma unroll
      for (int r2 = 0; r2 < 4; r2++) {
        const long row = m0 + i * 16 + quad * 4 + r2;
        if (row < 50000) {
          u16 ov[4] = { f2bf(aI[r2]), f2bf(aU[r2]), f2bf(aO[r2]), f2bf(aF[r2]) };
          *reinterpret_cast<ushort4*>(Gh + row * 512 + col * 4) =
              *reinterpret_cast<const ushort4*>(ov);
        }
      }
    }
  }
}

// ============ k_l3fused: L4 computed inline during staging, then L3 tree-LSTM step ============
// PM=32 parents / CM=64 children per block: LDS = 2 x 16 KB -> 4 blocks/CU (vs 2 at CM=128).
// Staging per child row r (an L4 node): vp = its vocab id, vc = its leaf child's id.
// gates = act(Ep[vp] + Gh[vc]); c4 = i*u + f*Cl[vc]; h4 = o*tanh(c4)  [identical rounding chain]
__global__ __launch_bounds__(256, 4) void k_l3fused(
    const int* __restrict__ sen, const u16* __restrict__ Ep,
    const u16* __restrict__ Gh, const u16* __restrict__ Cl,
    const u16* __restrict__ BfT, const u16* __restrict__ BihT,
    const u16* __restrict__ BuhT, const u16* __restrict__ BohT,
    u16* __restrict__ c_out, u16* __restrict__ h_out,
    long o0, long o1, long o2)
{
  constexpr int PM = 32, CM = 64, NCI = 4, RT = 2;
  __shared__ __align__(16) u16 ldsA[CM * 128];   // L4 h (swz), 16 KB
  __shared__ __align__(16) u16 ldsC[CM * 128];   // L4 c (swz), 16 KB
  __shared__ int sidP[PM];

  const int tid = threadIdx.x;
  const long p0 = (long)blockIdx.x * PM;
  const long cb = (long)blockIdx.x * CM;

  // ---- stage: compute L4 children in place (4 threads/row, 32 cols each) ----
  {
    const int r = tid >> 2, q = tid & 3;
    const size_t vp = (size_t)sen[o1 + cb + r];   // L4 node vocab id
    const size_t vc = (size_t)sen[o2 + cb + r];   // its leaf child's vocab id
    const u16* ep = Ep + vp * 512;
    const u16* gh = Gh + vc * 512;
    const u16* cl = Cl + vc * 128;
#pragma unroll
    for (int ii = 0; ii < 4; ii++) {              // 4 chunks x 8 cols
      const int c16 = q * 4 + ii;
      uint4 ev[4], gv[4];
#pragma unroll
      for (int k = 0; k < 4; k++) {
        ev[k] = *reinterpret_cast<const uint4*>(ep + c16 * 32 + k * 8);
        gv[k] = *reinterpret_cast<const uint4*>(gh + c16 * 32 + k * 8);
      }
      uint4 cvv = *reinterpret_cast<const uint4*>(cl + c16 * 8);
      const u16* cp = reinterpret_cast<const u16*>(&cvv);
      unsigned int hp[4], cpk[4];
#pragma unroll
      for (int k = 0; k < 4; k++) {               // 2 cols per k
        const u16* e = reinterpret_cast<const u16*>(&ev[k]);
        const u16* g = reinterpret_cast<const u16*>(&gv[k]);
        const float i0 = sigmoidf_(bf2f(e[0]) + bf2f(g[0]));
        const float u0 = tanhf_   (bf2f(e[1]) + bf2f(g[1]));
        const float og0= sigmoidf_(bf2f(e[2]) + bf2f(g[2]));
        const float f0 = sigmoidf_(bf2f(e[3]) + bf2f(g[3]));
        const float i1 = sigmoidf_(bf2f(e[4]) + bf2f(g[4]));
        const float u1 = tanhf_   (bf2f(e[5]) + bf2f(g[5]));
        const float og1= sigmoidf_(bf2f(e[6]) + bf2f(g[6]));
        const float f1 = sigmoidf_(bf2f(e[7]) + bf2f(g[7]));
        const float c0 = fmaf(i0, u0, f0 * bf2f(cp[k * 2]));
        const float c1 = fmaf(i1, u1, f1 * bf2f(cp[k * 2 + 1]));
        const float h0 = og0 * tanhf_(c0);
        const float h1 = og1 * tanhf_(c1);
        hp[k]  = f2bf_pk(h0, h1);
        cpk[k] = f2bf_pk(c0, c1);
      }
      *reinterpret_cast<uint4*>(&ldsA[swz128(r, c16)]) =
          *reinterpret_cast<const uint4*>(hp);
      *reinterpret_cast<uint4*>(&ldsC[swz128(r, c16)]) =
          *reinterpret_cast<const uint4*>(cpk);
    }
    if (tid < PM) sidP[tid] = sen[o0 + p0 + tid];
  }
  __syncthreads();

  const int lane = tid & 63, w = tid >> 6, l16 = lane & 15, quad = lane >> 4;

#pragma unroll
  for (int gl = 0; gl < 2; gl++) {
    const int col = w * 32 + gl * 16 + l16;
    bf16x8 bF[4], bI[4], bU[4], bO[4];
#pragma unroll
    for (int ks = 0; ks < 4; ks++) {
      const size_t bo_ = (size_t)col * 128 + ks * 32 + quad * 8;
      bF[ks] = *reinterpret_cast<const bf16x8*>(BfT + bo_);
      bI[ks] = *reinterpret_cast<const bf16x8*>(BihT + bo_);
      bU[ks] = *reinterpret_cast<const bf16x8*>(BuhT + bo_);
      bO[ks] = *reinterpret_cast<const bf16x8*>(BohT + bo_);
    }
#pragma unroll
    for (int i = 0; i < NCI; i++) {
      floatx4 aF = {0.f,0.f,0.f,0.f}, aI = {0.f,0.f,0.f,0.f};
      floatx4 aU = {0.f,0.f,0.f,0.f}, aO = {0.f,0.f,0.f,0.f};
#pragma unroll
      for (int ks = 0; ks < 4; ks++) {
        bf16x8 a = *reinterpret_cast<const bf16x8*>(&ldsA[swz128(i * 16 + l16, ks * 4 + quad)]);
        aF = __builtin_amdgcn_mfma_f32_16x16x32_bf16(a, bF[ks], aF, 0, 0, 0);
        aI = __builtin_amdgcn_mfma_f32_16x16x32_bf16(a, bI[ks], aI, 0, 0, 0);
        aU = __builtin_amdgcn_mfma_f32_16x16x32_bf16(a, bU[ks], aU, 0, 0, 0);
        aO = __builtin_amdgcn_mfma_f32_16x16x32_bf16(a, bO[ks], aO, 0, 0, 0);
      }
      const int rbase = i * 16 + quad * 4;
#pragma unroll
      for (int t = 0; t < 2; t++) {
        const int p = (rbase >> 1) + t;
        ushort4 g4 = *reinterpret_cast<const ushort4*>(Ep + (size_t)sidP[p] * 512 + col * 4);
        const float epf = bf2f(g4.w);
        float fsum = 0.f, isum = 0.f, usum = 0.f, osum = 0.f;
#pragma unroll
        for (int r2 = t * RT; r2 < t * RT + RT; r2++) {
          const int row = rbase + r2;
          const float cch = bf2f(ldsC[swze(row, col)]);
          fsum += sigmoidf_(aF[r2] + epf) * cch;
          isum += aI[r2]; usum += aU[r2]; osum += aO[r2];
        }
        const float c = sigmoidf_(isum + bf2f(g4.x)) * tanhf_(usum + bf2f(g4.y)) + fsum;
        const float h = sigmoidf_(osum + bf2f(g4.z)) * tanhf_(c);
        c_out[(p0 + p) * 128 + col] = f2bf(c);
        h_out[(p0 + p) * 128 + col] = f2bf(h);
      }
    }
  }
}

// ============ k_level: per-i-tile fused f/i/u/o (inner levels, computed children) ============
template<int LR>
__global__ __launch_bounds__(256, 4) void k_level(
    const int* __restrict__ sen, const u16* __restrict__ Ep,
    const u16* __restrict__ h_prev, const u16* __restrict__ c_prev,
    const u16* __restrict__ BfT, const u16* __restrict__ BihT,
    const u16* __restrict__ BuhT, const u16* __restrict__ BohT,
    u16* __restrict__ c_out, u16* __restrict__ h_out,
    long o0)
{
  constexpr int PM  = (LR == 2) ? 32 : 64;
  constexpr int CM  = PM << LR;
  constexpr int NCI = CM / 16;
  constexpr int RT  = 1 << LR;
  constexpr int RTI = 4 >> LR;         // parents per 4-row quad block
  constexpr int TPR = 256 / CM;        // staging threads per child row
  __shared__ __align__(16) u16 ldsA[CM * 128];   // child h (swz)
  __shared__ int sidP[PM];

  const int tid = threadIdx.x;
  const long p0 = (long)blockIdx.x * PM;
  const long cb = (long)blockIdx.x * CM;

  // ---- stage children ----
  {
    const int r = tid / TPR, q = tid % TPR;
    constexpr int CH = 16 / TPR;
    const u16* src = h_prev + (cb + r) * 128;
#pragma unroll
    for (int ii = 0; ii < CH; ii++) {
      const int c16 = q * CH + ii;
      *reinterpret_cast<uint4*>(&ldsA[swz128(r, c16)]) =
          *reinterpret_cast<const uint4*>(src + c16 * 8);
    }
    if (tid < PM) sidP[tid] = sen[o0 + p0 + tid];
  }
  __syncthreads();

  const int lane = tid & 63, w = tid >> 6, l16 = lane & 15, quad = lane >> 4;

#pragma unroll
  for (int gl = 0; gl < 2; gl++) {
    const int col = w * 32 + gl * 16 + l16;
    bf16x8 bF[4], bI[4], bU[4], bO[4];
#pragma unroll
    for (int ks = 0; ks < 4; ks++) {
      const size_t bo_ = (size_t)col * 128 + ks * 32 + quad * 8;
      bF[ks] = *reinterpret_cast<const bf16x8*>(BfT + bo_);
      bI[ks] = *reinterpret_cast<const bf16x8*>(BihT + bo_);
      bU[ks] = *reinterpret_cast<const bf16x8*>(BuhT + bo_);
      bO[ks] = *reinterpret_cast<const bf16x8*>(BohT + bo_);
    }
#pragma unroll
    for (int i = 0; i < NCI; i++) {
      floatx4 aF = {0.f,0.f,0.f,0.f}, aI = {0.f,0.f,0.f,0.f};
      floatx4 aU = {0.f,0.f,0.f,0.f}, aO = {0.f,0.f,0.f,0.f};
#pragma unroll
      for (int ks = 0; ks < 4; ks++) {
        bf16x8 a = *reinterpret_cast<const bf16x8*>(&ldsA[swz128(i * 16 + l16, ks * 4 + quad)]);
        aF = __builtin_amdgcn_mfma_f32_16x16x32_bf16(a, bF[ks], aF, 0, 0, 0);
        aI = __builtin_amdgcn_mfma_f32_16x16x32_bf16(a, bI[ks], aI, 0, 0, 0);
        aU = __builtin_amdgcn_mfma_f32_16x16x32_bf16(a, bU[ks], aU, 0, 0, 0);
        aO = __builtin_amdgcn_mfma_f32_16x16x32_bf16(a, bO[ks], aO, 0, 0, 0);
      }
      const int rbase = i * 16 + quad * 4;
#pragma unroll
      for (int t = 0; t < RTI; t++) {
        const int p = (rbase >> LR) + t;
        ushort4 g4 = *reinterpret_cast<const ushort4*>(Ep + (size_t)sidP[p] * 512 + col * 4);
        const float epf = bf2f(g4.w);
        float fsum = 0.f, isum = 0.f, usum = 0.f, osum = 0.f;
#pragma unroll
        for (int r2 = t * RT; r2 < t * RT + RT; r2++) {
          const int row = rbase + r2;
          const float cch = bf2f(c_prev[(cb + row) * 128 + col]);
          fsum += sigmoidf_(aF[r2] + epf) * cch;
          isum += aI[r2]; usum += aU[r2]; osum += aO[r2];
        }
        const float c = sigmoidf_(isum + bf2f(g4.x)) * tanhf_(usum + bf2f(g4.y)) + fsum;
        const float h = sigmoidf_(osum + bf2f(g4.z)) * tanhf_(c);
        c_out[(p0 + p) * 128 + col] = f2bf(c);
        h_out[(p0 + p) * 128 + col] = f2bf(h);
      }
    }
  }
}

// ---------- weight/bias prep ----------
__global__ void build_wallT(const float* __restrict__ Wix, const float* __restrict__ Wux,
                            const float* __restrict__ Wox, const float* __restrict__ Wfx,
                            u16* __restrict__ WT)
{
  int idx = blockIdx.x * 256 + threadIdx.x;   // 512*128
  int n = idx >> 7, k = idx & 127;
  int g = n >> 7, j = n & 127;
  const float* W = (g == 0) ? Wix : (g == 1) ? Wux : (g == 2) ? Wox : Wfx;
  WT[idx] = f2bf(W[k * 128 + j]);
}

__global__ void build_bsum(const float* __restrict__ b_ix, const float* __restrict__ b_ih,
                           const float* __restrict__ b_ux, const float* __restrict__ b_uh,
                           const float* __restrict__ b_ox, const float* __restrict__ b_oh,
                           const float* __restrict__ b_fx, const float* __restrict__ b_fh,
                           float* __restrict__ bsum)
{
  int n = blockIdx.x * 256 + threadIdx.x;   // 512
  int g = n >> 7, j = n & 127;
  float v = (g == 0) ? b_ix[j] + b_ih[j] : (g == 1) ? b_ux[j] + b_uh[j]
          : (g == 2) ? b_ox[j] + b_oh[j] : b_fx[j] + b_fh[j];
  bsum[n] = v;
}

__global__ void build_bt128(const float* __restrict__ W, u16* __restrict__ BT) {
  int idx = blockIdx.x * 256 + threadIdx.x;   // 128*128
  int n = idx >> 7, k = idx & 127;
  BT[idx] = f2bf(W[k * 128 + n]);
}

// ---------- output projection (4096 x 4, tiny) ----------
__global__ void out_proj(const u16* __restrict__ h_root, const float* __restrict__ W_out,
                         const float* __restrict__ b_out, float* __restrict__ out)
{
  int idx = blockIdx.x * 256 + threadIdx.x;   // 4096*4
  int n = idx >> 2, cls = idx & 3;
  float s = b_out[cls];
  for (int k = 0; k < 128; k++)
    s += bf2f(h_root[(long)n * 128 + k]) * W_out[k * 4 + cls];
  out[idx] = s;
}

extern "C" void kernel_launch(void* const* d_in, const int* in_sizes, int n_in,
                              void* d_out, int out_size, void* d_ws, size_t ws_size,
                              hipStream_t stream)
{
  const int*   sen  = (const int*)d_in[0];
  const float* emb  = (const float*)d_in[1];
  const float* W_ix = (const float*)d_in[2];  const float* b_ix = (const float*)d_in[3];
  const float* W_ih = (const float*)d_in[4];  const float* b_ih = (const float*)d_in[5];
  const float* W_fx = (const float*)d_in[6];  const float* b_fx = (const float*)d_in[7];
  const float* W_fh = (const float*)d_in[8];  const float* b_fh = (const float*)d_in[9];
  const float* W_ox = (const float*)d_in[10]; const float* b_ox = (const float*)d_in[11];
  const float* W_oh = (const float*)d_in[12]; const float* b_oh = (const float*)d_in[13];
  const float* W_ux = (const float*)d_in[14]; const float* b_ux = (const float*)d_in[15];
  const float* W_uh = (const float*)d_in[16]; const float* b_uh = (const float*)d_in[17];
  const float* W_out= (const float*)d_in[18]; const float* b_out= (const float*)d_in[19];
  float* out = (float*)d_out;

  // ---- workspace: every buffer distinct (no aliasing; L4 h/c never materialized) ----
  const size_t EPB = (size_t)50000 * 512 * 2;       // Ep / Gh bytes (51.2 MB each)
  const size_t CLB = (size_t)50000 * 128 * 2;       // Cl bytes (12.8 MB)
  const size_t H3  = (size_t)131072 * 128 * 2;      // 33.55 MB each
  const size_t H2  = (size_t)65536  * 128 * 2;
  const size_t H1  = (size_t)16384  * 128 * 2;
  const size_t H0  = (size_t)4096   * 128 * 2;
  const size_t need = 2 * EPB + CLB + 2 * (H3 + H2 + H1 + H0)
                    + (size_t)512 * 128 * 2 + 4 * (size_t)128 * 128 * 2 + 512 * 4 + 8192;
  fprintf(stderr, "[tree_lstm] ws_size=%zu need=%zu\n", ws_size, need);
  if (ws_size < need) {
    fprintf(stderr, "[tree_lstm] INSUFFICIENT WORKSPACE — skipping launch\n");
    return;
  }
  char* ws = (char*)d_ws;
  size_t off = 0;
  auto take = [&](size_t bytes) { char* p = ws + off; off += (bytes + 255) & ~(size_t)255; return p; };
  u16* Ep = (u16*)take(EPB);
  u16* Gh = (u16*)take(EPB);
  u16* Cl = (u16*)take(CLB);
  u16* h3 = (u16*)take(H3);  u16* c3 = (u16*)take(H3);
  u16* h2 = (u16*)take(H2);  u16* c2 = (u16*)take(H2);
  u16* h1 = (u16*)take(H1);  u16* c1 = (u16*)take(H1);
  u16* h0 = (u16*)take(H0);  u16* c0 = (u16*)take(H0);
  u16* WallT = (u16*)take((size_t)512 * 128 * 2);
  u16* BihT = (u16*)take((size_t)128 * 128 * 2);
  u16* BuhT = (u16*)take((size_t)128 * 128 * 2);
  u16* BohT = (u16*)take((size_t)128 * 128 * 2);
  u16* BfhT = (u16*)take((size_t)128 * 128 * 2);
  float* bsum = (float*)take(512 * 4);

  // ---- prep ----
  build_wallT<<<256, 256, 0, stream>>>(W_ix, W_ux, W_ox, W_fx, WallT);
  build_bsum<<<2, 256, 0, stream>>>(b_ix, b_ih, b_ux, b_uh, b_ox, b_oh, b_fx, b_fh, bsum);
  build_bt128<<<64, 256, 0, stream>>>(W_ih, BihT);
  build_bt128<<<64, 256, 0, stream>>>(W_uh, BuhT);
  build_bt128<<<64, 256, 0, stream>>>(W_oh, BohT);
  build_bt128<<<64, 256, 0, stream>>>(W_fh, BfhT);
  proj_e<<<391, 256, 0, stream>>>(emb, WallT, bsum, Ep);
  proj_hc<<<391, 256, 0, stream>>>(Ep, BihT, BuhT, BohT, BfhT, Cl, Gh);

  const long LOFF[6] = {0, 4096, 20480, 86016, 217088, 479232};

  // L3 (131072 parents, 32/block) with L4 (ratio-1 leaf level) computed inline in staging
  k_l3fused<<<4096, 256, 0, stream>>>(sen, Ep, Gh, Cl,
      BfhT, BihT, BuhT, BohT, c3, h3, LOFF[3], LOFF[4], LOFF[5]);
  // L2 (65536, ratio 2)
  k_level<1><<<1024, 256, 0, stream>>>(sen, Ep, h3, c3,
      BfhT, BihT, BuhT, BohT, c2, h2, LOFF[2]);
  // L1 (16384, ratio 4)
  k_level<2><<<512, 256, 0, stream>>>(sen, Ep, h2, c2,
      BfhT, BihT, BuhT, BohT, c1, h1, LOFF[1]);
  // L0 (4096, ratio 4)
  k_level<2><<<128, 256, 0, stream>>>(sen, Ep, h1, c1,
      BfhT, BihT, BuhT, BohT, c0, h0, LOFF[0]);

  out_proj<<<64, 256, 0, stream>>>(h0, W_out, b_out, out);
}

// Round 6
// 545.256 us; speedup vs baseline: 1.2861x; 1.2861x over previous
//
#include <hip/hip_runtime.h>
#include <hip/hip_bf16.h>
#include <cstdio>

typedef unsigned short u16;
typedef __bf16 bf16x8 __attribute__((ext_vector_type(8)));
typedef float  floatx4 __attribute__((ext_vector_type(4)));

// ---------- scalar helpers ----------
__device__ __forceinline__ float bf2f(u16 u) {
  union { unsigned int i; float f; } v; v.i = ((unsigned int)u) << 16; return v.f;
}
__device__ __forceinline__ u16 f2bf(float f) {
  union { float f; unsigned int i; } v; v.f = f;
  unsigned int x = v.i;
  return (u16)((x + 0x7fffu + ((x >> 16) & 1u)) >> 16);   // RNE
}
__device__ __forceinline__ unsigned int f2bf_pk(float a, float b) {   // [lo=a, hi=b]
  __hip_bfloat162 h = __float22bfloat162_rn(make_float2(a, b));
  union { __hip_bfloat162 h; unsigned int u; } v; v.h = h; return v.u;
}
// fast gates: v_rcp (~1 ulp) + native exp — no IEEE div
__device__ __forceinline__ float sigmoidf_(float x) {
  return __builtin_amdgcn_rcpf(1.f + __expf(-x));
}
__device__ __forceinline__ float tanhf_(float x) {
  return fmaf(-2.f, __builtin_amdgcn_rcpf(1.f + __expf(2.f * x)), 1.f);
}

// LDS swizzle, 128-elem rows, 16B chunks: chunk' = chunk ^ (row&15)
__device__ __forceinline__ int swz128(int row, int c16) {
  return row * 128 + ((c16 ^ (row & 15)) << 3);
}
// element-level access into swizzled rows
__device__ __forceinline__ int swze(int row, int col) {
  return row * 128 + (((((col >> 3)) ^ (row & 15)) << 3) | (col & 7));
}

// ============ proj_e: Ep[v][col][4] = {i,u,o,f} pre-acts + biases (gate-interleaved) ============
__global__ __launch_bounds__(256, 2) void proj_e(
    const float* __restrict__ emb, const u16* __restrict__ WT,
    const float* __restrict__ bsum, u16* __restrict__ Ep)
{
  __shared__ __align__(16) u16 ldsA[128 * 128];
  const int tid = threadIdx.x;
  const long m0 = (long)blockIdx.x * 128;
  {
    const int r = tid >> 1, half = tid & 1;
    long row = m0 + r; if (row > 49999) row = 49999;
    const float* src = emb + row * 128 + half * 64;
#pragma unroll
    for (int i = 0; i < 8; i++) {
      float4 v0 = *reinterpret_cast<const float4*>(src + i * 8);
      float4 v1 = *reinterpret_cast<const float4*>(src + i * 8 + 4);
      unsigned int ov[4] = { f2bf_pk(v0.x, v0.y), f2bf_pk(v0.z, v0.w),
                             f2bf_pk(v1.x, v1.y), f2bf_pk(v1.z, v1.w) };
      *reinterpret_cast<uint4*>(&ldsA[swz128(r, half * 8 + i)]) =
          *reinterpret_cast<const uint4*>(ov);
    }
  }
  __syncthreads();
  const int lane = tid & 63, w = tid >> 6, l16 = lane & 15, quad = lane >> 4;
#pragma unroll
  for (int half = 0; half < 2; half++) {
    const int col = w * 32 + half * 16 + l16;
    bf16x8 bI[4], bU[4], bO[4], bF[4];
#pragma unroll
    for (int ks = 0; ks < 4; ks++) {
      const size_t o_ = ks * 32 + quad * 8;
      bI[ks] = *reinterpret_cast<const bf16x8*>(WT + (size_t)(0   + col) * 128 + o_);
      bU[ks] = *reinterpret_cast<const bf16x8*>(WT + (size_t)(128 + col) * 128 + o_);
      bO[ks] = *reinterpret_cast<const bf16x8*>(WT + (size_t)(256 + col) * 128 + o_);
      bF[ks] = *reinterpret_cast<const bf16x8*>(WT + (size_t)(384 + col) * 128 + o_);
    }
    const float bi = bsum[col], bu = bsum[128 + col], bo = bsum[256 + col], bf = bsum[384 + col];
#pragma unroll
    for (int i = 0; i < 8; i++) {
      floatx4 aI = {0.f,0.f,0.f,0.f}, aU = {0.f,0.f,0.f,0.f};
      floatx4 aO = {0.f,0.f,0.f,0.f}, aF = {0.f,0.f,0.f,0.f};
#pragma unroll
      for (int ks = 0; ks < 4; ks++) {
        bf16x8 a = *reinterpret_cast<const bf16x8*>(&ldsA[swz128(i * 16 + l16, ks * 4 + quad)]);
        aI = __builtin_amdgcn_mfma_f32_16x16x32_bf16(a, bI[ks], aI, 0, 0, 0);
        aU = __builtin_amdgcn_mfma_f32_16x16x32_bf16(a, bU[ks], aU, 0, 0, 0);
        aO = __builtin_amdgcn_mfma_f32_16x16x32_bf16(a, bO[ks], aO, 0, 0, 0);
        aF = __builtin_amdgcn_mfma_f32_16x16x32_bf16(a, bF[ks], aF, 0, 0, 0);
      }
#pragma unroll
      for (int r2 = 0; r2 < 4; r2++) {
        const long row = m0 + i * 16 + quad * 4 + r2;
        if (row < 50000) {
          u16 ov[4] = { f2bf(aI[r2] + bi), f2bf(aU[r2] + bu),
                        f2bf(aO[r2] + bo), f2bf(aF[r2] + bf) };
          *reinterpret_cast<ushort4*>(Ep + row * 512 + col * 4) =
              *reinterpret_cast<const ushort4*>(ov);
        }
      }
    }
  }
}

// ============ proj_hc: fused leaf activations + h-side projection ============
// Staging: Ep[v] -> leaf h (LDS, swizzled) and leaf c -> Cl[v] (global).
// MFMA:    Gh[v][col][4] = {i,u,o,f} h-side pre-acts = Hleaf[v] @ W_*h (no bias).
__global__ __launch_bounds__(256, 2) void proj_hc(
    const u16* __restrict__ Ep,
    const u16* __restrict__ BihT, const u16* __restrict__ BuhT,
    const u16* __restrict__ BohT, const u16* __restrict__ BfT,
    u16* __restrict__ Cl, u16* __restrict__ Gh)
{
  __shared__ __align__(16) u16 ldsA[128 * 128];
  const int tid = threadIdx.x;
  const long m0 = (long)blockIdx.x * 128;
  {
    const int r = tid >> 1, half = tid & 1;
    long row = m0 + r;
    const bool ok = (row < 50000); if (!ok) row = 49999;
    const u16* src = Ep + row * 512 + half * 256;
#pragma unroll
    for (int i = 0; i < 8; i++) {
      uint4 v[4];
#pragma unroll
      for (int k = 0; k < 4; k++)
        v[k] = *reinterpret_cast<const uint4*>(src + i * 32 + k * 8);
      unsigned int hp[4], cp[4];
#pragma unroll
      for (int k = 0; k < 4; k++) {      // each uint4 = 2 cols x {i,u,o,f}
        const u16* p = reinterpret_cast<const u16*>(&v[k]);
        float c0 = sigmoidf_(bf2f(p[0])) * tanhf_(bf2f(p[1]));
        float c1 = sigmoidf_(bf2f(p[4])) * tanhf_(bf2f(p[5]));
        float h0 = sigmoidf_(bf2f(p[2])) * tanhf_(c0);
        float h1 = sigmoidf_(bf2f(p[6])) * tanhf_(c1);
        cp[k] = f2bf_pk(c0, c1);
        hp[k] = f2bf_pk(h0, h1);
      }
      *reinterpret_cast<uint4*>(&ldsA[swz128(r, half * 8 + i)]) =
          *reinterpret_cast<const uint4*>(hp);
      if (ok)
        *reinterpret_cast<uint4*>(Cl + row * 128 + half * 64 + i * 8) =
            *reinterpret_cast<const uint4*>(cp);
    }
  }
  __syncthreads();
  const int lane = tid & 63, w = tid >> 6, l16 = lane & 15, quad = lane >> 4;
#pragma unroll
  for (int half = 0; half < 2; half++) {
    const int col = w * 32 + half * 16 + l16;
    bf16x8 bI[4], bU[4], bO[4], bF[4];
#pragma unroll
    for (int ks = 0; ks < 4; ks++) {
      const size_t o_ = (size_t)col * 128 + ks * 32 + quad * 8;
      bI[ks] = *reinterpret_cast<const bf16x8*>(BihT + o_);
      bU[ks] = *reinterpret_cast<const bf16x8*>(BuhT + o_);
      bO[ks] = *reinterpret_cast<const bf16x8*>(BohT + o_);
      bF[ks] = *reinterpret_cast<const bf16x8*>(BfT  + o_);
    }
#pragma unroll
    for (int i = 0; i < 8; i++) {
      floatx4 aI = {0.f,0.f,0.f,0.f}, aU = {0.f,0.f,0.f,0.f};
      floatx4 aO = {0.f,0.f,0.f,0.f}, aF = {0.f,0.f,0.f,0.f};
#pragma unroll
      for (int ks = 0; ks < 4; ks++) {
        bf16x8 a = *reinterpret_cast<const bf16x8*>(&ldsA[swz128(i * 16 + l16, ks * 4 + quad)]);
        aI = __builtin_amdgcn_mfma_f32_16x16x32_bf16(a, bI[ks], aI, 0, 0, 0);
        aU = __builtin_amdgcn_mfma_f32_16x16x32_bf16(a, bU[ks], aU, 0, 0, 0);
        aO = __builtin_amdgcn_mfma_f32_16x16x32_bf16(a, bO[ks], aO, 0, 0, 0);
        aF = __builtin_amdgcn_mfma_f32_16x16x32_bf16(a, bF[ks], aF, 0, 0, 0);
      }
#pragma unroll
      for (int r2 = 0; r2 < 4; r2++) {
        const long row = m0 + i * 16 + quad * 4 + r2;
        if (row < 50000) {
          u16 ov[4] = { f2bf(aI[r2]), f2bf(aU[r2]), f2bf(aO[r2]), f2bf(aF[r2]) };
          *reinterpret_cast<ushort4*>(Gh + row * 512 + col * 4) =
              *reinterpret_cast<const ushort4*>(ov);
        }
      }
    }
  }
}

// ============ k_l3fused: L4 computed inline during staging, then L3 tree-LSTM step ============
// PM=32 parents / CM=64 children per block: LDS = 2 x 16 KB + sid = 32.4 KB.
// launch_bounds(256,2): NO forced VGPR cap (round-5's (256,4) forced 64 VGPR -> massive scratch
// spill, WRITE_SIZE 73->334 MB). At ~120 VGPR and 32.4 KB LDS the natural HW occupancy is
// 4 blocks/CU (min(512/120, 160/32.4) = 4) — we get the MLP without the spill.
__global__ __launch_bounds__(256, 2) void k_l3fused(
    const int* __restrict__ sen, const u16* __restrict__ Ep,
    const u16* __restrict__ Gh, const u16* __restrict__ Cl,
    const u16* __restrict__ BfT, const u16* __restrict__ BihT,
    const u16* __restrict__ BuhT, const u16* __restrict__ BohT,
    u16* __restrict__ c_out, u16* __restrict__ h_out,
    long o0, long o1, long o2)
{
  constexpr int PM = 32, CM = 64, NCI = 4, RT = 2;
  __shared__ __align__(16) u16 ldsA[CM * 128];   // L4 h (swz), 16 KB
  __shared__ __align__(16) u16 ldsC[CM * 128];   // L4 c (swz), 16 KB
  __shared__ int sidP[PM];

  const int tid = threadIdx.x;
  const long p0 = (long)blockIdx.x * PM;
  const long cb = (long)blockIdx.x * CM;

  // ---- stage: compute L4 children in place (4 threads/row, 32 cols each) ----
  {
    const int r = tid >> 2, q = tid & 3;
    const size_t vp = (size_t)sen[o1 + cb + r];   // L4 node vocab id
    const size_t vc = (size_t)sen[o2 + cb + r];   // its leaf child's vocab id
    const u16* ep = Ep + vp * 512;
    const u16* gh = Gh + vc * 512;
    const u16* cl = Cl + vc * 128;
#pragma unroll
    for (int ii = 0; ii < 4; ii++) {              // 4 chunks x 8 cols
      const int c16 = q * 4 + ii;
      uint4 ev[4], gv[4];
#pragma unroll
      for (int k = 0; k < 4; k++) {
        ev[k] = *reinterpret_cast<const uint4*>(ep + c16 * 32 + k * 8);
        gv[k] = *reinterpret_cast<const uint4*>(gh + c16 * 32 + k * 8);
      }
      uint4 cvv = *reinterpret_cast<const uint4*>(cl + c16 * 8);
      const u16* cp = reinterpret_cast<const u16*>(&cvv);
      unsigned int hp[4], cpk[4];
#pragma unroll
      for (int k = 0; k < 4; k++) {               // 2 cols per k
        const u16* e = reinterpret_cast<const u16*>(&ev[k]);
        const u16* g = reinterpret_cast<const u16*>(&gv[k]);
        const float i0 = sigmoidf_(bf2f(e[0]) + bf2f(g[0]));
        const float u0 = tanhf_   (bf2f(e[1]) + bf2f(g[1]));
        const float og0= sigmoidf_(bf2f(e[2]) + bf2f(g[2]));
        const float f0 = sigmoidf_(bf2f(e[3]) + bf2f(g[3]));
        const float i1 = sigmoidf_(bf2f(e[4]) + bf2f(g[4]));
        const float u1 = tanhf_   (bf2f(e[5]) + bf2f(g[5]));
        const float og1= sigmoidf_(bf2f(e[6]) + bf2f(g[6]));
        const float f1 = sigmoidf_(bf2f(e[7]) + bf2f(g[7]));
        const float c0 = fmaf(i0, u0, f0 * bf2f(cp[k * 2]));
        const float c1 = fmaf(i1, u1, f1 * bf2f(cp[k * 2 + 1]));
        const float h0 = og0 * tanhf_(c0);
        const float h1 = og1 * tanhf_(c1);
        hp[k]  = f2bf_pk(h0, h1);
        cpk[k] = f2bf_pk(c0, c1);
      }
      *reinterpret_cast<uint4*>(&ldsA[swz128(r, c16)]) =
          *reinterpret_cast<const uint4*>(hp);
      *reinterpret_cast<uint4*>(&ldsC[swz128(r, c16)]) =
          *reinterpret_cast<const uint4*>(cpk);
    }
    if (tid < PM) sidP[tid] = sen[o0 + p0 + tid];
  }
  __syncthreads();

  const int lane = tid & 63, w = tid >> 6, l16 = lane & 15, quad = lane >> 4;

#pragma unroll
  for (int gl = 0; gl < 2; gl++) {
    const int col = w * 32 + gl * 16 + l16;
    bf16x8 bF[4], bI[4], bU[4], bO[4];
#pragma unroll
    for (int ks = 0; ks < 4; ks++) {
      const size_t bo_ = (size_t)col * 128 + ks * 32 + quad * 8;
      bF[ks] = *reinterpret_cast<const bf16x8*>(BfT + bo_);
      bI[ks] = *reinterpret_cast<const bf16x8*>(BihT + bo_);
      bU[ks] = *reinterpret_cast<const bf16x8*>(BuhT + bo_);
      bO[ks] = *reinterpret_cast<const bf16x8*>(BohT + bo_);
    }
#pragma unroll
    for (int i = 0; i < NCI; i++) {
      floatx4 aF = {0.f,0.f,0.f,0.f}, aI = {0.f,0.f,0.f,0.f};
      floatx4 aU = {0.f,0.f,0.f,0.f}, aO = {0.f,0.f,0.f,0.f};
#pragma unroll
      for (int ks = 0; ks < 4; ks++) {
        bf16x8 a = *reinterpret_cast<const bf16x8*>(&ldsA[swz128(i * 16 + l16, ks * 4 + quad)]);
        aF = __builtin_amdgcn_mfma_f32_16x16x32_bf16(a, bF[ks], aF, 0, 0, 0);
        aI = __builtin_amdgcn_mfma_f32_16x16x32_bf16(a, bI[ks], aI, 0, 0, 0);
        aU = __builtin_amdgcn_mfma_f32_16x16x32_bf16(a, bU[ks], aU, 0, 0, 0);
        aO = __builtin_amdgcn_mfma_f32_16x16x32_bf16(a, bO[ks], aO, 0, 0, 0);
      }
      const int rbase = i * 16 + quad * 4;
#pragma unroll
      for (int t = 0; t < 2; t++) {
        const int p = (rbase >> 1) + t;
        ushort4 g4 = *reinterpret_cast<const ushort4*>(Ep + (size_t)sidP[p] * 512 + col * 4);
        const float epf = bf2f(g4.w);
        float fsum = 0.f, isum = 0.f, usum = 0.f, osum = 0.f;
#pragma unroll
        for (int r2 = t * RT; r2 < t * RT + RT; r2++) {
          const int row = rbase + r2;
          const float cch = bf2f(ldsC[swze(row, col)]);
          fsum += sigmoidf_(aF[r2] + epf) * cch;
          isum += aI[r2]; usum += aU[r2]; osum += aO[r2];
        }
        const float c = sigmoidf_(isum + bf2f(g4.x)) * tanhf_(usum + bf2f(g4.y)) + fsum;
        const float h = sigmoidf_(osum + bf2f(g4.z)) * tanhf_(c);
        c_out[(p0 + p) * 128 + col] = f2bf(c);
        h_out[(p0 + p) * 128 + col] = f2bf(h);
      }
    }
  }
}

// ============ k_level: per-i-tile fused f/i/u/o (inner levels, computed children) ============
template<int LR>
__global__ __launch_bounds__(256, 2) void k_level(
    const int* __restrict__ sen, const u16* __restrict__ Ep,
    const u16* __restrict__ h_prev, const u16* __restrict__ c_prev,
    const u16* __restrict__ BfT, const u16* __restrict__ BihT,
    const u16* __restrict__ BuhT, const u16* __restrict__ BohT,
    u16* __restrict__ c_out, u16* __restrict__ h_out,
    long o0)
{
  constexpr int PM  = (LR == 2) ? 32 : 64;
  constexpr int CM  = PM << LR;
  constexpr int NCI = CM / 16;
  constexpr int RT  = 1 << LR;
  constexpr int RTI = 4 >> LR;         // parents per 4-row quad block
  constexpr int TPR = 256 / CM;        // staging threads per child row
  __shared__ __align__(16) u16 ldsA[CM * 128];   // child h (swz)
  __shared__ int sidP[PM];

  const int tid = threadIdx.x;
  const long p0 = (long)blockIdx.x * PM;
  const long cb = (long)blockIdx.x * CM;

  // ---- stage children ----
  {
    const int r = tid / TPR, q = tid % TPR;
    constexpr int CH = 16 / TPR;
    const u16* src = h_prev + (cb + r) * 128;
#pragma unroll
    for (int ii = 0; ii < CH; ii++) {
      const int c16 = q * CH + ii;
      *reinterpret_cast<uint4*>(&ldsA[swz128(r, c16)]) =
          *reinterpret_cast<const uint4*>(src + c16 * 8);
    }
    if (tid < PM) sidP[tid] = sen[o0 + p0 + tid];
  }
  __syncthreads();

  const int lane = tid & 63, w = tid >> 6, l16 = lane & 15, quad = lane >> 4;

#pragma unroll
  for (int gl = 0; gl < 2; gl++) {
    const int col = w * 32 + gl * 16 + l16;
    bf16x8 bF[4], bI[4], bU[4], bO[4];
#pragma unroll
    for (int ks = 0; ks < 4; ks++) {
      const size_t bo_ = (size_t)col * 128 + ks * 32 + quad * 8;
      bF[ks] = *reinterpret_cast<const bf16x8*>(BfT + bo_);
      bI[ks] = *reinterpret_cast<const bf16x8*>(BihT + bo_);
      bU[ks] = *reinterpret_cast<const bf16x8*>(BuhT + bo_);
      bO[ks] = *reinterpret_cast<const bf16x8*>(BohT + bo_);
    }
#pragma unroll
    for (int i = 0; i < NCI; i++) {
      floatx4 aF = {0.f,0.f,0.f,0.f}, aI = {0.f,0.f,0.f,0.f};
      floatx4 aU = {0.f,0.f,0.f,0.f}, aO = {0.f,0.f,0.f,0.f};
#pragma unroll
      for (int ks = 0; ks < 4; ks++) {
        bf16x8 a = *reinterpret_cast<const bf16x8*>(&ldsA[swz128(i * 16 + l16, ks * 4 + quad)]);
        aF = __builtin_amdgcn_mfma_f32_16x16x32_bf16(a, bF[ks], aF, 0, 0, 0);
        aI = __builtin_amdgcn_mfma_f32_16x16x32_bf16(a, bI[ks], aI, 0, 0, 0);
        aU = __builtin_amdgcn_mfma_f32_16x16x32_bf16(a, bU[ks], aU, 0, 0, 0);
        aO = __builtin_amdgcn_mfma_f32_16x16x32_bf16(a, bO[ks], aO, 0, 0, 0);
      }
      const int rbase = i * 16 + quad * 4;
#pragma unroll
      for (int t = 0; t < RTI; t++) {
        const int p = (rbase >> LR) + t;
        ushort4 g4 = *reinterpret_cast<const ushort4*>(Ep + (size_t)sidP[p] * 512 + col * 4);
        const float epf = bf2f(g4.w);
        float fsum = 0.f, isum = 0.f, usum = 0.f, osum = 0.f;
#pragma unroll
        for (int r2 = t * RT; r2 < t * RT + RT; r2++) {
          const int row = rbase + r2;
          const float cch = bf2f(c_prev[(cb + row) * 128 + col]);
          fsum += sigmoidf_(aF[r2] + epf) * cch;
          isum += aI[r2]; usum += aU[r2]; osum += aO[r2];
        }
        const float c = sigmoidf_(isum + bf2f(g4.x)) * tanhf_(usum + bf2f(g4.y)) + fsum;
        const float h = sigmoidf_(osum + bf2f(g4.z)) * tanhf_(c);
        c_out[(p0 + p) * 128 + col] = f2bf(c);
        h_out[(p0 + p) * 128 + col] = f2bf(h);
      }
    }
  }
}

// ---------- weight/bias prep ----------
__global__ void build_wallT(const float* __restrict__ Wix, const float* __restrict__ Wux,
                            const float* __restrict__ Wox, const float* __restrict__ Wfx,
                            u16* __restrict__ WT)
{
  int idx = blockIdx.x * 256 + threadIdx.x;   // 512*128
  int n = idx >> 7, k = idx & 127;
  int g = n >> 7, j = n & 127;
  const float* W = (g == 0) ? Wix : (g == 1) ? Wux : (g == 2) ? Wox : Wfx;
  WT[idx] = f2bf(W[k * 128 + j]);
}

__global__ void build_bsum(const float* __restrict__ b_ix, const float* __restrict__ b_ih,
                           const float* __restrict__ b_ux, const float* __restrict__ b_uh,
                           const float* __restrict__ b_ox, const float* __restrict__ b_oh,
                           const float* __restrict__ b_fx, const float* __restrict__ b_fh,
                           float* __restrict__ bsum)
{
  int n = blockIdx.x * 256 + threadIdx.x;   // 512
  int g = n >> 7, j = n & 127;
  float v = (g == 0) ? b_ix[j] + b_ih[j] : (g == 1) ? b_ux[j] + b_uh[j]
          : (g == 2) ? b_ox[j] + b_oh[j] : b_fx[j] + b_fh[j];
  bsum[n] = v;
}

__global__ void build_bt128(const float* __restrict__ W, u16* __restrict__ BT) {
  int idx = blockIdx.x * 256 + threadIdx.x;   // 128*128
  int n = idx >> 7, k = idx & 127;
  BT[idx] = f2bf(W[k * 128 + n]);
}

// ---------- output projection (4096 x 4, tiny) ----------
__global__ void out_proj(const u16* __restrict__ h_root, const float* __restrict__ W_out,
                         const float* __restrict__ b_out, float* __restrict__ out)
{
  int idx = blockIdx.x * 256 + threadIdx.x;   // 4096*4
  int n = idx >> 2, cls = idx & 3;
  float s = b_out[cls];
  for (int k = 0; k < 128; k++)
    s += bf2f(h_root[(long)n * 128 + k]) * W_out[k * 4 + cls];
  out[idx] = s;
}

extern "C" void kernel_launch(void* const* d_in, const int* in_sizes, int n_in,
                              void* d_out, int out_size, void* d_ws, size_t ws_size,
                              hipStream_t stream)
{
  const int*   sen  = (const int*)d_in[0];
  const float* emb  = (const float*)d_in[1];
  const float* W_ix = (const float*)d_in[2];  const float* b_ix = (const float*)d_in[3];
  const float* W_ih = (const float*)d_in[4];  const float* b_ih = (const float*)d_in[5];
  const float* W_fx = (const float*)d_in[6];  const float* b_fx = (const float*)d_in[7];
  const float* W_fh = (const float*)d_in[8];  const float* b_fh = (const float*)d_in[9];
  const float* W_ox = (const float*)d_in[10]; const float* b_ox = (const float*)d_in[11];
  const float* W_oh = (const float*)d_in[12]; const float* b_oh = (const float*)d_in[13];
  const float* W_ux = (const float*)d_in[14]; const float* b_ux = (const float*)d_in[15];
  const float* W_uh = (const float*)d_in[16]; const float* b_uh = (const float*)d_in[17];
  const float* W_out= (const float*)d_in[18]; const float* b_out= (const float*)d_in[19];
  float* out = (float*)d_out;

  // ---- workspace: every buffer distinct (no aliasing; L4 h/c never materialized) ----
  const size_t EPB = (size_t)50000 * 512 * 2;       // Ep / Gh bytes (51.2 MB each)
  const size_t CLB = (size_t)50000 * 128 * 2;       // Cl bytes (12.8 MB)
  const size_t H3  = (size_t)131072 * 128 * 2;      // 33.55 MB each
  const size_t H2  = (size_t)65536  * 128 * 2;
  const size_t H1  = (size_t)16384  * 128 * 2;
  const size_t H0  = (size_t)4096   * 128 * 2;
  const size_t need = 2 * EPB + CLB + 2 * (H3 + H2 + H1 + H0)
                    + (size_t)512 * 128 * 2 + 4 * (size_t)128 * 128 * 2 + 512 * 4 + 8192;
  fprintf(stderr, "[tree_lstm] ws_size=%zu need=%zu\n", ws_size, need);
  if (ws_size < need) {
    fprintf(stderr, "[tree_lstm] INSUFFICIENT WORKSPACE — skipping launch\n");
    return;
  }
  char* ws = (char*)d_ws;
  size_t off = 0;
  auto take = [&](size_t bytes) { char* p = ws + off; off += (bytes + 255) & ~(size_t)255; return p; };
  u16* Ep = (u16*)take(EPB);
  u16* Gh = (u16*)take(EPB);
  u16* Cl = (u16*)take(CLB);
  u16* h3 = (u16*)take(H3);  u16* c3 = (u16*)take(H3);
  u16* h2 = (u16*)take(H2);  u16* c2 = (u16*)take(H2);
  u16* h1 = (u16*)take(H1);  u16* c1 = (u16*)take(H1);
  u16* h0 = (u16*)take(H0);  u16* c0 = (u16*)take(H0);
  u16* WallT = (u16*)take((size_t)512 * 128 * 2);
  u16* BihT = (u16*)take((size_t)128 * 128 * 2);
  u16* BuhT = (u16*)take((size_t)128 * 128 * 2);
  u16* BohT = (u16*)take((size_t)128 * 128 * 2);
  u16* BfhT = (u16*)take((size_t)128 * 128 * 2);
  float* bsum = (float*)take(512 * 4);

  // ---- prep ----
  build_wallT<<<256, 256, 0, stream>>>(W_ix, W_ux, W_ox, W_fx, WallT);
  build_bsum<<<2, 256, 0, stream>>>(b_ix, b_ih, b_ux, b_uh, b_ox, b_oh, b_fx, b_fh, bsum);
  build_bt128<<<64, 256, 0, stream>>>(W_ih, BihT);
  build_bt128<<<64, 256, 0, stream>>>(W_uh, BuhT);
  build_bt128<<<64, 256, 0, stream>>>(W_oh, BohT);
  build_bt128<<<64, 256, 0, stream>>>(W_fh, BfhT);
  proj_e<<<391, 256, 0, stream>>>(emb, WallT, bsum, Ep);
  proj_hc<<<391, 256, 0, stream>>>(Ep, BihT, BuhT, BohT, BfhT, Cl, Gh);

  const long LOFF[6] = {0, 4096, 20480, 86016, 217088, 479232};

  // L3 (131072 parents, 32/block) with L4 (ratio-1 leaf level) computed inline in staging
  k_l3fused<<<4096, 256, 0, stream>>>(sen, Ep, Gh, Cl,
      BfhT, BihT, BuhT, BohT, c3, h3, LOFF[3], LOFF[4], LOFF[5]);
  // L2 (65536, ratio 2)
  k_level<1><<<1024, 256, 0, stream>>>(sen, Ep, h3, c3,
      BfhT, BihT, BuhT, BohT, c2, h2, LOFF[2]);
  // L1 (16384, ratio 4)
  k_level<2><<<512, 256, 0, stream>>>(sen, Ep, h2, c2,
      BfhT, BihT, BuhT, BohT, c1, h1, LOFF[1]);
  // L0 (4096, ratio 4)
  k_level<2><<<128, 256, 0, stream>>>(sen, Ep, h1, c1,
      BfhT, BihT, BuhT, BohT, c0, h0, LOFF[0]);

  out_proj<<<64, 256, 0, stream>>>(h0, W_out, b_out, out);
}

// Round 7
// 536.642 us; speedup vs baseline: 1.3067x; 1.0161x over previous
//
#include <hip/hip_runtime.h>
#include <hip/hip_bf16.h>
#include <cstdio>

typedef unsigned short u16;
typedef __bf16 bf16x8 __attribute__((ext_vector_type(8)));
typedef float  floatx4 __attribute__((ext_vector_type(4)));

// ---------- scalar helpers ----------
__device__ __forceinline__ float bf2f(u16 u) {
  union { unsigned int i; float f; } v; v.i = ((unsigned int)u) << 16; return v.f;
}
__device__ __forceinline__ u16 f2bf(float f) {
  union { float f; unsigned int i; } v; v.f = f;
  unsigned int x = v.i;
  return (u16)((x + 0x7fffu + ((x >> 16) & 1u)) >> 16);   // RNE
}
__device__ __forceinline__ unsigned int f2bf_pk(float a, float b) {   // [lo=a, hi=b]
  __hip_bfloat162 h = __float22bfloat162_rn(make_float2(a, b));
  union { __hip_bfloat162 h; unsigned int u; } v; v.h = h; return v.u;
}
// fast gates: v_rcp (~1 ulp) + native exp — no IEEE div
__device__ __forceinline__ float sigmoidf_(float x) {
  return __builtin_amdgcn_rcpf(1.f + __expf(-x));
}
__device__ __forceinline__ float tanhf_(float x) {
  return fmaf(-2.f, __builtin_amdgcn_rcpf(1.f + __expf(2.f * x)), 1.f);
}

// LDS swizzle, 128-elem rows, 16B chunks: chunk' = chunk ^ (row&15)
__device__ __forceinline__ int swz128(int row, int c16) {
  return row * 128 + ((c16 ^ (row & 15)) << 3);
}
// element-level access into swizzled rows
__device__ __forceinline__ int swze(int row, int col) {
  return row * 128 + (((((col >> 3)) ^ (row & 15)) << 3) | (col & 7));
}

// ============ proj_e: Ep[v][col][4] = {i,u,o,f} pre-acts + biases (gate-interleaved) ============
__global__ __launch_bounds__(256, 2) void proj_e(
    const float* __restrict__ emb, const u16* __restrict__ WT,
    const float* __restrict__ bsum, u16* __restrict__ Ep)
{
  __shared__ __align__(16) u16 ldsA[128 * 128];
  const int tid = threadIdx.x;
  const long m0 = (long)blockIdx.x * 128;
  {
    const int r = tid >> 1, half = tid & 1;
    long row = m0 + r; if (row > 49999) row = 49999;
    const float* src = emb + row * 128 + half * 64;
#pragma unroll
    for (int i = 0; i < 8; i++) {
      float4 v0 = *reinterpret_cast<const float4*>(src + i * 8);
      float4 v1 = *reinterpret_cast<const float4*>(src + i * 8 + 4);
      unsigned int ov[4] = { f2bf_pk(v0.x, v0.y), f2bf_pk(v0.z, v0.w),
                             f2bf_pk(v1.x, v1.y), f2bf_pk(v1.z, v1.w) };
      *reinterpret_cast<uint4*>(&ldsA[swz128(r, half * 8 + i)]) =
          *reinterpret_cast<const uint4*>(ov);
    }
  }
  __syncthreads();
  const int lane = tid & 63, w = tid >> 6, l16 = lane & 15, quad = lane >> 4;
#pragma unroll
  for (int half = 0; half < 2; half++) {
    const int col = w * 32 + half * 16 + l16;
    bf16x8 bI[4], bU[4], bO[4], bF[4];
#pragma unroll
    for (int ks = 0; ks < 4; ks++) {
      const size_t o_ = ks * 32 + quad * 8;
      bI[ks] = *reinterpret_cast<const bf16x8*>(WT + (size_t)(0   + col) * 128 + o_);
      bU[ks] = *reinterpret_cast<const bf16x8*>(WT + (size_t)(128 + col) * 128 + o_);
      bO[ks] = *reinterpret_cast<const bf16x8*>(WT + (size_t)(256 + col) * 128 + o_);
      bF[ks] = *reinterpret_cast<const bf16x8*>(WT + (size_t)(384 + col) * 128 + o_);
    }
    const float bi = bsum[col], bu = bsum[128 + col], bo = bsum[256 + col], bf = bsum[384 + col];
#pragma unroll
    for (int i = 0; i < 8; i++) {
      floatx4 aI = {0.f,0.f,0.f,0.f}, aU = {0.f,0.f,0.f,0.f};
      floatx4 aO = {0.f,0.f,0.f,0.f}, aF = {0.f,0.f,0.f,0.f};
#pragma unroll
      for (int ks = 0; ks < 4; ks++) {
        bf16x8 a = *reinterpret_cast<const bf16x8*>(&ldsA[swz128(i * 16 + l16, ks * 4 + quad)]);
        aI = __builtin_amdgcn_mfma_f32_16x16x32_bf16(a, bI[ks], aI, 0, 0, 0);
        aU = __builtin_amdgcn_mfma_f32_16x16x32_bf16(a, bU[ks], aU, 0, 0, 0);
        aO = __builtin_amdgcn_mfma_f32_16x16x32_bf16(a, bO[ks], aO, 0, 0, 0);
        aF = __builtin_amdgcn_mfma_f32_16x16x32_bf16(a, bF[ks], aF, 0, 0, 0);
      }
#pragma unroll
      for (int r2 = 0; r2 < 4; r2++) {
        const long row = m0 + i * 16 + quad * 4 + r2;
        if (row < 50000) {
          u16 ov[4] = { f2bf(aI[r2] + bi), f2bf(aU[r2] + bu),
                        f2bf(aO[r2] + bo), f2bf(aF[r2] + bf) };
          *reinterpret_cast<ushort4*>(Ep + row * 512 + col * 4) =
              *reinterpret_cast<const ushort4*>(ov);
        }
      }
    }
  }
}

// ============ embf: bf16 copy of the embedding table (Xb[v][128]) ============
__global__ void embf(const float* __restrict__ emb, u16* __restrict__ Xb)
{
  const long idx = (long)blockIdx.x * 256 + threadIdx.x;   // 1.6M threads x 4 elems
  float4 v = *reinterpret_cast<const float4*>(emb + idx * 4);
  unsigned int o[2] = { f2bf_pk(v.x, v.y), f2bf_pk(v.z, v.w) };
  *reinterpret_cast<uint2*>(Xb + idx * 4) = *reinterpret_cast<const uint2*>(o);
}

// ============ leaf_hc: vocab-level leaf activations Hl[v][128], Cl[v][128] ============
__global__ void leaf_hc(const u16* __restrict__ Ep,
                        u16* __restrict__ Hl, u16* __restrict__ Cl)
{
  const int tid = threadIdx.x;
  const int r = tid >> 6, c2 = tid & 63;           // 4 vocab rows/block, 2 cols/thread
  const size_t v = (size_t)blockIdx.x * 4 + r;     // grid = 12500 -> covers 50000 exactly
  uint4 g = *reinterpret_cast<const uint4*>(Ep + v * 512 + (size_t)c2 * 8);
  const u16* p = reinterpret_cast<const u16*>(&g); // {i,u,o,f} x 2 cols
  float c0 = sigmoidf_(bf2f(p[0])) * tanhf_(bf2f(p[1]));
  float c1 = sigmoidf_(bf2f(p[4])) * tanhf_(bf2f(p[5]));
  float h0 = sigmoidf_(bf2f(p[2])) * tanhf_(c0);
  float h1 = sigmoidf_(bf2f(p[6])) * tanhf_(c1);
  *reinterpret_cast<unsigned int*>(Hl + v * 128 + c2 * 2) = f2bf_pk(h0, h1);
  *reinterpret_cast<unsigned int*>(Cl + v * 128 + c2 * 2) = f2bf_pk(c0, c1);
}

// ============ k_l3fused v2: narrow gathers + in-kernel L4 projection, then L3 step ============
// Phase 0 (stage): per L4 node gather Xb[vp] (256B) + Hl[vc] (256B) + Cl[vc] (256B)
//                  -> 768B/node vs 2.25KB/node of the table design (FETCH was the bottleneck).
// Phase 1: L4 preacts via MFMA: acc = x@W*x + hl@W*h (f32), gates = act(acc + bsum);
//          c4 = i*u + f*cl (overwrites Cl tile in place; exclusive (row,col) ownership),
//          h4 = o*tanh(c4) -> ldsA.
// Phase 2: L3 step on h4/c4 (identical to previous back half; parent preacts from Ep).
__global__ __launch_bounds__(256, 2) void k_l3fused(
    const int* __restrict__ sen, const u16* __restrict__ Ep,
    const u16* __restrict__ Xb, const u16* __restrict__ Hl, const u16* __restrict__ Cl,
    const u16* __restrict__ WxT, const float* __restrict__ bsum,
    const u16* __restrict__ BfT, const u16* __restrict__ BihT,
    const u16* __restrict__ BuhT, const u16* __restrict__ BohT,
    u16* __restrict__ c_out, u16* __restrict__ h_out,
    long o0, long o1, long o2)
{
  constexpr int PM = 32, CM = 64, NCI = 4, RT = 2;
  __shared__ __align__(16) u16 ldsX[CM * 128];   // L4-node x (bf16 emb, swz) 16 KB
  __shared__ __align__(16) u16 ldsH[CM * 128];   // leaf h (swz) 16 KB
  __shared__ __align__(16) u16 ldsC[CM * 128];   // leaf c -> L4 c in place (swz) 16 KB
  __shared__ __align__(16) u16 ldsA[CM * 128];   // L4 h (swz) 16 KB
  __shared__ int sidP[PM];

  const int tid = threadIdx.x;
  const long p0 = (long)blockIdx.x * PM;
  const long cb = (long)blockIdx.x * CM;

  // ---- phase 0: stage (4 threads/row, 32 cols each) ----
  {
    const int r = tid >> 2, q = tid & 3;
    const size_t vp = (size_t)sen[o1 + cb + r];   // L4 node vocab id
    const size_t vc = (size_t)sen[o2 + cb + r];   // its leaf child's vocab id
    const u16* xb = Xb + vp * 128;
    const u16* hl = Hl + vc * 128;
    const u16* cl = Cl + vc * 128;
#pragma unroll
    for (int ii = 0; ii < 4; ii++) {
      const int c16 = q * 4 + ii;
      *reinterpret_cast<uint4*>(&ldsX[swz128(r, c16)]) =
          *reinterpret_cast<const uint4*>(xb + c16 * 8);
      *reinterpret_cast<uint4*>(&ldsH[swz128(r, c16)]) =
          *reinterpret_cast<const uint4*>(hl + c16 * 8);
      *reinterpret_cast<uint4*>(&ldsC[swz128(r, c16)]) =
          *reinterpret_cast<const uint4*>(cl + c16 * 8);
    }
    if (tid < PM) sidP[tid] = sen[o0 + p0 + tid];
  }
  __syncthreads();

  const int lane = tid & 63, w = tid >> 6, l16 = lane & 15, quad = lane >> 4;

  // ---- phase 1: L4 gates via MFMA, elementwise -> h4 (ldsA) / c4 (ldsC in place) ----
#pragma unroll
  for (int gl = 0; gl < 2; gl++) {
    const int col = w * 32 + gl * 16 + l16;
    bf16x8 xI[4], xU[4], xO[4], xF[4], hI[4], hU[4], hO[4], hF[4];
#pragma unroll
    for (int ks = 0; ks < 4; ks++) {
      const size_t xo = ks * 32 + quad * 8;
      xI[ks] = *reinterpret_cast<const bf16x8*>(WxT + (size_t)(0   + col) * 128 + xo);
      xU[ks] = *reinterpret_cast<const bf16x8*>(WxT + (size_t)(128 + col) * 128 + xo);
      xO[ks] = *reinterpret_cast<const bf16x8*>(WxT + (size_t)(256 + col) * 128 + xo);
      xF[ks] = *reinterpret_cast<const bf16x8*>(WxT + (size_t)(384 + col) * 128 + xo);
      const size_t ho = (size_t)col * 128 + xo;
      hI[ks] = *reinterpret_cast<const bf16x8*>(BihT + ho);
      hU[ks] = *reinterpret_cast<const bf16x8*>(BuhT + ho);
      hO[ks] = *reinterpret_cast<const bf16x8*>(BohT + ho);
      hF[ks] = *reinterpret_cast<const bf16x8*>(BfT  + ho);
    }
    const float bi = bsum[col], bu = bsum[128 + col], bo = bsum[256 + col], bf = bsum[384 + col];
#pragma unroll
    for (int i = 0; i < NCI; i++) {
      floatx4 aI = {0.f,0.f,0.f,0.f}, aU = {0.f,0.f,0.f,0.f};
      floatx4 aO = {0.f,0.f,0.f,0.f}, aF = {0.f,0.f,0.f,0.f};
#pragma unroll
      for (int ks = 0; ks < 4; ks++) {
        bf16x8 ax = *reinterpret_cast<const bf16x8*>(&ldsX[swz128(i * 16 + l16, ks * 4 + quad)]);
        aI = __builtin_amdgcn_mfma_f32_16x16x32_bf16(ax, xI[ks], aI, 0, 0, 0);
        aU = __builtin_amdgcn_mfma_f32_16x16x32_bf16(ax, xU[ks], aU, 0, 0, 0);
        aO = __builtin_amdgcn_mfma_f32_16x16x32_bf16(ax, xO[ks], aO, 0, 0, 0);
        aF = __builtin_amdgcn_mfma_f32_16x16x32_bf16(ax, xF[ks], aF, 0, 0, 0);
      }
#pragma unroll
      for (int ks = 0; ks < 4; ks++) {
        bf16x8 ah = *reinterpret_cast<const bf16x8*>(&ldsH[swz128(i * 16 + l16, ks * 4 + quad)]);
        aI = __builtin_amdgcn_mfma_f32_16x16x32_bf16(ah, hI[ks], aI, 0, 0, 0);
        aU = __builtin_amdgcn_mfma_f32_16x16x32_bf16(ah, hU[ks], aU, 0, 0, 0);
        aO = __builtin_amdgcn_mfma_f32_16x16x32_bf16(ah, hO[ks], aO, 0, 0, 0);
        aF = __builtin_amdgcn_mfma_f32_16x16x32_bf16(ah, hF[ks], aF, 0, 0, 0);
      }
      const int rbase = i * 16 + quad * 4;
#pragma unroll
      for (int r2 = 0; r2 < 4; r2++) {
        const int row = rbase + r2;
        const float iv = sigmoidf_(aI[r2] + bi);
        const float uv = tanhf_   (aU[r2] + bu);
        const float ov = sigmoidf_(aO[r2] + bo);
        const float fv = sigmoidf_(aF[r2] + bf);
        const int sl = swze(row, col);
        const float clv = bf2f(ldsC[sl]);
        const float c4 = fmaf(iv, uv, fv * clv);
        const float h4 = ov * tanhf_(c4);
        ldsC[sl] = f2bf(c4);     // in place: this (row,col) owned exclusively by this lane
        ldsA[sl] = f2bf(h4);
      }
    }
  }
  __syncthreads();

  // ---- phase 2: L3 tree-LSTM step (unchanged back half) ----
#pragma unroll
  for (int gl = 0; gl < 2; gl++) {
    const int col = w * 32 + gl * 16 + l16;
    bf16x8 bF[4], bI[4], bU[4], bO[4];
#pragma unroll
    for (int ks = 0; ks < 4; ks++) {
      const size_t bo_ = (size_t)col * 128 + ks * 32 + quad * 8;
      bF[ks] = *reinterpret_cast<const bf16x8*>(BfT + bo_);
      bI[ks] = *reinterpret_cast<const bf16x8*>(BihT + bo_);
      bU[ks] = *reinterpret_cast<const bf16x8*>(BuhT + bo_);
      bO[ks] = *reinterpret_cast<const bf16x8*>(BohT + bo_);
    }
#pragma unroll
    for (int i = 0; i < NCI; i++) {
      floatx4 aF = {0.f,0.f,0.f,0.f}, aI = {0.f,0.f,0.f,0.f};
      floatx4 aU = {0.f,0.f,0.f,0.f}, aO = {0.f,0.f,0.f,0.f};
#pragma unroll
      for (int ks = 0; ks < 4; ks++) {
        bf16x8 a = *reinterpret_cast<const bf16x8*>(&ldsA[swz128(i * 16 + l16, ks * 4 + quad)]);
        aF = __builtin_amdgcn_mfma_f32_16x16x32_bf16(a, bF[ks], aF, 0, 0, 0);
        aI = __builtin_amdgcn_mfma_f32_16x16x32_bf16(a, bI[ks], aI, 0, 0, 0);
        aU = __builtin_amdgcn_mfma_f32_16x16x32_bf16(a, bU[ks], aU, 0, 0, 0);
        aO = __builtin_amdgcn_mfma_f32_16x16x32_bf16(a, bO[ks], aO, 0, 0, 0);
      }
      const int rbase = i * 16 + quad * 4;
#pragma unroll
      for (int t = 0; t < 2; t++) {
        const int p = (rbase >> 1) + t;
        ushort4 g4 = *reinterpret_cast<const ushort4*>(Ep + (size_t)sidP[p] * 512 + col * 4);
        const float epf = bf2f(g4.w);
        float fsum = 0.f, isum = 0.f, usum = 0.f, osum = 0.f;
#pragma unroll
        for (int r2 = t * RT; r2 < t * RT + RT; r2++) {
          const int row = rbase + r2;
          const float cch = bf2f(ldsC[swze(row, col)]);
          fsum += sigmoidf_(aF[r2] + epf) * cch;
          isum += aI[r2]; usum += aU[r2]; osum += aO[r2];
        }
        const float c = sigmoidf_(isum + bf2f(g4.x)) * tanhf_(usum + bf2f(g4.y)) + fsum;
        const float h = sigmoidf_(osum + bf2f(g4.z)) * tanhf_(c);
        c_out[(p0 + p) * 128 + col] = f2bf(c);
        h_out[(p0 + p) * 128 + col] = f2bf(h);
      }
    }
  }
}

// ============ k_level: per-i-tile fused f/i/u/o (inner levels, computed children) ============
template<int LR>
__global__ __launch_bounds__(256, 2) void k_level(
    const int* __restrict__ sen, const u16* __restrict__ Ep,
    const u16* __restrict__ h_prev, const u16* __restrict__ c_prev,
    const u16* __restrict__ BfT, const u16* __restrict__ BihT,
    const u16* __restrict__ BuhT, const u16* __restrict__ BohT,
    u16* __restrict__ c_out, u16* __restrict__ h_out,
    long o0)
{
  constexpr int PM  = (LR == 2) ? 32 : 64;
  constexpr int CM  = PM << LR;
  constexpr int NCI = CM / 16;
  constexpr int RT  = 1 << LR;
  constexpr int RTI = 4 >> LR;         // parents per 4-row quad block
  constexpr int TPR = 256 / CM;        // staging threads per child row
  __shared__ __align__(16) u16 ldsA[CM * 128];   // child h (swz)
  __shared__ int sidP[PM];

  const int tid = threadIdx.x;
  const long p0 = (long)blockIdx.x * PM;
  const long cb = (long)blockIdx.x * CM;

  // ---- stage children ----
  {
    const int r = tid / TPR, q = tid % TPR;
    constexpr int CH = 16 / TPR;
    const u16* src = h_prev + (cb + r) * 128;
#pragma unroll
    for (int ii = 0; ii < CH; ii++) {
      const int c16 = q * CH + ii;
      *reinterpret_cast<uint4*>(&ldsA[swz128(r, c16)]) =
          *reinterpret_cast<const uint4*>(src + c16 * 8);
    }
    if (tid < PM) sidP[tid] = sen[o0 + p0 + tid];
  }
  __syncthreads();

  const int lane = tid & 63, w = tid >> 6, l16 = lane & 15, quad = lane >> 4;

#pragma unroll
  for (int gl = 0; gl < 2; gl++) {
    const int col = w * 32 + gl * 16 + l16;
    bf16x8 bF[4], bI[4], bU[4], bO[4];
#pragma unroll
    for (int ks = 0; ks < 4; ks++) {
      const size_t bo_ = (size_t)col * 128 + ks * 32 + quad * 8;
      bF[ks] = *reinterpret_cast<const bf16x8*>(BfT + bo_);
      bI[ks] = *reinterpret_cast<const bf16x8*>(BihT + bo_);
      bU[ks] = *reinterpret_cast<const bf16x8*>(BuhT + bo_);
      bO[ks] = *reinterpret_cast<const bf16x8*>(BohT + bo_);
    }
#pragma unroll
    for (int i = 0; i < NCI; i++) {
      floatx4 aF = {0.f,0.f,0.f,0.f}, aI = {0.f,0.f,0.f,0.f};
      floatx4 aU = {0.f,0.f,0.f,0.f}, aO = {0.f,0.f,0.f,0.f};
#pragma unroll
      for (int ks = 0; ks < 4; ks++) {
        bf16x8 a = *reinterpret_cast<const bf16x8*>(&ldsA[swz128(i * 16 + l16, ks * 4 + quad)]);
        aF = __builtin_amdgcn_mfma_f32_16x16x32_bf16(a, bF[ks], aF, 0, 0, 0);
        aI = __builtin_amdgcn_mfma_f32_16x16x32_bf16(a, bI[ks], aI, 0, 0, 0);
        aU = __builtin_amdgcn_mfma_f32_16x16x32_bf16(a, bU[ks], aU, 0, 0, 0);
        aO = __builtin_amdgcn_mfma_f32_16x16x32_bf16(a, bO[ks], aO, 0, 0, 0);
      }
      const int rbase = i * 16 + quad * 4;
#pragma unroll
      for (int t = 0; t < RTI; t++) {
        const int p = (rbase >> LR) + t;
        ushort4 g4 = *reinterpret_cast<const ushort4*>(Ep + (size_t)sidP[p] * 512 + col * 4);
        const float epf = bf2f(g4.w);
        float fsum = 0.f, isum = 0.f, usum = 0.f, osum = 0.f;
#pragma unroll
        for (int r2 = t * RT; r2 < t * RT + RT; r2++) {
          const int row = rbase + r2;
          const float cch = bf2f(c_prev[(cb + row) * 128 + col]);
          fsum += sigmoidf_(aF[r2] + epf) * cch;
          isum += aI[r2]; usum += aU[r2]; osum += aO[r2];
        }
        const float c = sigmoidf_(isum + bf2f(g4.x)) * tanhf_(usum + bf2f(g4.y)) + fsum;
        const float h = sigmoidf_(osum + bf2f(g4.z)) * tanhf_(c);
        c_out[(p0 + p) * 128 + col] = f2bf(c);
        h_out[(p0 + p) * 128 + col] = f2bf(h);
      }
    }
  }
}

// ---------- weight/bias prep ----------
__global__ void build_wallT(const float* __restrict__ Wix, const float* __restrict__ Wux,
                            const float* __restrict__ Wox, const float* __restrict__ Wfx,
                            u16* __restrict__ WT)
{
  int idx = blockIdx.x * 256 + threadIdx.x;   // 512*128
  int n = idx >> 7, k = idx & 127;
  int g = n >> 7, j = n & 127;
  const float* W = (g == 0) ? Wix : (g == 1) ? Wux : (g == 2) ? Wox : Wfx;
  WT[idx] = f2bf(W[k * 128 + j]);
}

__global__ void build_bsum(const float* __restrict__ b_ix, const float* __restrict__ b_ih,
                           const float* __restrict__ b_ux, const float* __restrict__ b_uh,
                           const float* __restrict__ b_ox, const float* __restrict__ b_oh,
                           const float* __restrict__ b_fx, const float* __restrict__ b_fh,
                           float* __restrict__ bsum)
{
  int n = blockIdx.x * 256 + threadIdx.x;   // 512
  int g = n >> 7, j = n & 127;
  float v = (g == 0) ? b_ix[j] + b_ih[j] : (g == 1) ? b_ux[j] + b_uh[j]
          : (g == 2) ? b_ox[j] + b_oh[j] : b_fx[j] + b_fh[j];
  bsum[n] = v;
}

__global__ void build_bt128(const float* __restrict__ W, u16* __restrict__ BT) {
  int idx = blockIdx.x * 256 + threadIdx.x;   // 128*128
  int n = idx >> 7, k = idx & 127;
  BT[idx] = f2bf(W[k * 128 + n]);
}

// ---------- output projection (4096 x 4, tiny) ----------
__global__ void out_proj(const u16* __restrict__ h_root, const float* __restrict__ W_out,
                         const float* __restrict__ b_out, float* __restrict__ out)
{
  int idx = blockIdx.x * 256 + threadIdx.x;   // 4096*4
  int n = idx >> 2, cls = idx & 3;
  float s = b_out[cls];
  for (int k = 0; k < 128; k++)
    s += bf2f(h_root[(long)n * 128 + k]) * W_out[k * 4 + cls];
  out[idx] = s;
}

extern "C" void kernel_launch(void* const* d_in, const int* in_sizes, int n_in,
                              void* d_out, int out_size, void* d_ws, size_t ws_size,
                              hipStream_t stream)
{
  const int*   sen  = (const int*)d_in[0];
  const float* emb  = (const float*)d_in[1];
  const float* W_ix = (const float*)d_in[2];  const float* b_ix = (const float*)d_in[3];
  const float* W_ih = (const float*)d_in[4];  const float* b_ih = (const float*)d_in[5];
  const float* W_fx = (const float*)d_in[6];  const float* b_fx = (const float*)d_in[7];
  const float* W_fh = (const float*)d_in[8];  const float* b_fh = (const float*)d_in[9];
  const float* W_ox = (const float*)d_in[10]; const float* b_ox = (const float*)d_in[11];
  const float* W_oh = (const float*)d_in[12]; const float* b_oh = (const float*)d_in[13];
  const float* W_ux = (const float*)d_in[14]; const float* b_ux = (const float*)d_in[15];
  const float* W_uh = (const float*)d_in[16]; const float* b_uh = (const float*)d_in[17];
  const float* W_out= (const float*)d_in[18]; const float* b_out= (const float*)d_in[19];
  float* out = (float*)d_out;

  // ---- workspace ----
  const size_t EPB = (size_t)50000 * 512 * 2;       // Ep (51.2 MB)
  const size_t TBB = (size_t)50000 * 128 * 2;       // Xb / Hl / Cl (12.8 MB each)
  const size_t H3  = (size_t)131072 * 128 * 2;      // 33.55 MB each
  const size_t H2  = (size_t)65536  * 128 * 2;
  const size_t H1  = (size_t)16384  * 128 * 2;
  const size_t H0  = (size_t)4096   * 128 * 2;
  const size_t need = EPB + 3 * TBB + 2 * (H3 + H2 + H1 + H0)
                    + (size_t)512 * 128 * 2 + 4 * (size_t)128 * 128 * 2 + 512 * 4 + 8192;
  fprintf(stderr, "[tree_lstm] ws_size=%zu need=%zu\n", ws_size, need);
  if (ws_size < need) {
    fprintf(stderr, "[tree_lstm] INSUFFICIENT WORKSPACE — skipping launch\n");
    return;
  }
  char* ws = (char*)d_ws;
  size_t off = 0;
  auto take = [&](size_t bytes) { char* p = ws + off; off += (bytes + 255) & ~(size_t)255; return p; };
  u16* Ep = (u16*)take(EPB);
  u16* Xb = (u16*)take(TBB);
  u16* Hl = (u16*)take(TBB);
  u16* Cl = (u16*)take(TBB);
  u16* h3 = (u16*)take(H3);  u16* c3 = (u16*)take(H3);
  u16* h2 = (u16*)take(H2);  u16* c2 = (u16*)take(H2);
  u16* h1 = (u16*)take(H1);  u16* c1 = (u16*)take(H1);
  u16* h0 = (u16*)take(H0);  u16* c0 = (u16*)take(H0);
  u16* WallT = (u16*)take((size_t)512 * 128 * 2);
  u16* BihT = (u16*)take((size_t)128 * 128 * 2);
  u16* BuhT = (u16*)take((size_t)128 * 128 * 2);
  u16* BohT = (u16*)take((size_t)128 * 128 * 2);
  u16* BfhT = (u16*)take((size_t)128 * 128 * 2);
  float* bsum = (float*)take(512 * 4);

  // ---- prep ----
  build_wallT<<<256, 256, 0, stream>>>(W_ix, W_ux, W_ox, W_fx, WallT);
  build_bsum<<<2, 256, 0, stream>>>(b_ix, b_ih, b_ux, b_uh, b_ox, b_oh, b_fx, b_fh, bsum);
  build_bt128<<<64, 256, 0, stream>>>(W_ih, BihT);
  build_bt128<<<64, 256, 0, stream>>>(W_uh, BuhT);
  build_bt128<<<64, 256, 0, stream>>>(W_oh, BohT);
  build_bt128<<<64, 256, 0, stream>>>(W_fh, BfhT);
  proj_e<<<391, 256, 0, stream>>>(emb, WallT, bsum, Ep);
  embf<<<6250, 256, 0, stream>>>(emb, Xb);           // 50000*128/4/256
  leaf_hc<<<12500, 256, 0, stream>>>(Ep, Hl, Cl);

  const long LOFF[6] = {0, 4096, 20480, 86016, 217088, 479232};

  // L3 (131072 parents) with L4 computed in-kernel from narrow Xb/Hl/Cl gathers
  k_l3fused<<<4096, 256, 0, stream>>>(sen, Ep, Xb, Hl, Cl, WallT, bsum,
      BfhT, BihT, BuhT, BohT, c3, h3, LOFF[3], LOFF[4], LOFF[5]);
  // L2 (65536, ratio 2)
  k_level<1><<<1024, 256, 0, stream>>>(sen, Ep, h3, c3,
      BfhT, BihT, BuhT, BohT, c2, h2, LOFF[2]);
  // L1 (16384, ratio 4)
  k_level<2><<<512, 256, 0, stream>>>(sen, Ep, h2, c2,
      BfhT, BihT, BuhT, BohT, c1, h1, LOFF[1]);
  // L0 (4096, ratio 4)
  k_level<2><<<128, 256, 0, stream>>>(sen, Ep, h1, c1,
      BfhT, BihT, BuhT, BohT, c0, h0, LOFF[0]);

  out_proj<<<64, 256, 0, stream>>>(h0, W_out, b_out, out);
}

// Round 8
// 521.849 us; speedup vs baseline: 1.3438x; 1.0283x over previous
//
#include <hip/hip_runtime.h>
#include <hip/hip_bf16.h>
#include <cstdio>

typedef unsigned short u16;
typedef __bf16 bf16x8 __attribute__((ext_vector_type(8)));
typedef float  floatx4 __attribute__((ext_vector_type(4)));

// ---------- scalar helpers ----------
__device__ __forceinline__ float bf2f(u16 u) {
  union { unsigned int i; float f; } v; v.i = ((unsigned int)u) << 16; return v.f;
}
__device__ __forceinline__ u16 f2bf(float f) {
  union { float f; unsigned int i; } v; v.f = f;
  unsigned int x = v.i;
  return (u16)((x + 0x7fffu + ((x >> 16) & 1u)) >> 16);   // RNE
}
__device__ __forceinline__ unsigned int f2bf_pk(float a, float b) {   // [lo=a, hi=b]
  __hip_bfloat162 h = __float22bfloat162_rn(make_float2(a, b));
  union { __hip_bfloat162 h; unsigned int u; } v; v.h = h; return v.u;
}
// fast gates: v_rcp (~1 ulp) + native exp — no IEEE div
__device__ __forceinline__ float sigmoidf_(float x) {
  return __builtin_amdgcn_rcpf(1.f + __expf(-x));
}
__device__ __forceinline__ float tanhf_(float x) {
  return fmaf(-2.f, __builtin_amdgcn_rcpf(1.f + __expf(2.f * x)), 1.f);
}

// LDS swizzle, 128-elem rows, 16B chunks: chunk' = chunk ^ (row&15)
__device__ __forceinline__ int swz128(int row, int c16) {
  return row * 128 + ((c16 ^ (row & 15)) << 3);
}
// element-level access into swizzled rows
__device__ __forceinline__ int swze(int row, int col) {
  return row * 128 + (((((col >> 3)) ^ (row & 15)) << 3) | (col & 7));
}

// ============ proj_e: Ep[v][col][4] = {i,u,o,f} pre-acts + biases (gate-interleaved) ============
__global__ __launch_bounds__(256, 2) void proj_e(
    const float* __restrict__ emb, const u16* __restrict__ WT,
    const float* __restrict__ bsum, u16* __restrict__ Ep)
{
  __shared__ __align__(16) u16 ldsA[128 * 128];
  const int tid = threadIdx.x;
  const long m0 = (long)blockIdx.x * 128;
  {
    const int r = tid >> 1, half = tid & 1;
    long row = m0 + r; if (row > 49999) row = 49999;
    const float* src = emb + row * 128 + half * 64;
#pragma unroll
    for (int i = 0; i < 8; i++) {
      float4 v0 = *reinterpret_cast<const float4*>(src + i * 8);
      float4 v1 = *reinterpret_cast<const float4*>(src + i * 8 + 4);
      unsigned int ov[4] = { f2bf_pk(v0.x, v0.y), f2bf_pk(v0.z, v0.w),
                             f2bf_pk(v1.x, v1.y), f2bf_pk(v1.z, v1.w) };
      *reinterpret_cast<uint4*>(&ldsA[swz128(r, half * 8 + i)]) =
          *reinterpret_cast<const uint4*>(ov);
    }
  }
  __syncthreads();
  const int lane = tid & 63, w = tid >> 6, l16 = lane & 15, quad = lane >> 4;
#pragma unroll
  for (int half = 0; half < 2; half++) {
    const int col = w * 32 + half * 16 + l16;
    bf16x8 bI[4], bU[4], bO[4], bF[4];
#pragma unroll
    for (int ks = 0; ks < 4; ks++) {
      const size_t o_ = ks * 32 + quad * 8;
      bI[ks] = *reinterpret_cast<const bf16x8*>(WT + (size_t)(0   + col) * 128 + o_);
      bU[ks] = *reinterpret_cast<const bf16x8*>(WT + (size_t)(128 + col) * 128 + o_);
      bO[ks] = *reinterpret_cast<const bf16x8*>(WT + (size_t)(256 + col) * 128 + o_);
      bF[ks] = *reinterpret_cast<const bf16x8*>(WT + (size_t)(384 + col) * 128 + o_);
    }
    const float bi = bsum[col], bu = bsum[128 + col], bo = bsum[256 + col], bf = bsum[384 + col];
#pragma unroll
    for (int i = 0; i < 8; i++) {
      floatx4 aI = {0.f,0.f,0.f,0.f}, aU = {0.f,0.f,0.f,0.f};
      floatx4 aO = {0.f,0.f,0.f,0.f}, aF = {0.f,0.f,0.f,0.f};
#pragma unroll
      for (int ks = 0; ks < 4; ks++) {
        bf16x8 a = *reinterpret_cast<const bf16x8*>(&ldsA[swz128(i * 16 + l16, ks * 4 + quad)]);
        aI = __builtin_amdgcn_mfma_f32_16x16x32_bf16(a, bI[ks], aI, 0, 0, 0);
        aU = __builtin_amdgcn_mfma_f32_16x16x32_bf16(a, bU[ks], aU, 0, 0, 0);
        aO = __builtin_amdgcn_mfma_f32_16x16x32_bf16(a, bO[ks], aO, 0, 0, 0);
        aF = __builtin_amdgcn_mfma_f32_16x16x32_bf16(a, bF[ks], aF, 0, 0, 0);
      }
#pragma unroll
      for (int r2 = 0; r2 < 4; r2++) {
        const long row = m0 + i * 16 + quad * 4 + r2;
        if (row < 50000) {
          u16 ov[4] = { f2bf(aI[r2] + bi), f2bf(aU[r2] + bu),
                        f2bf(aO[r2] + bo), f2bf(aF[r2] + bf) };
          *reinterpret_cast<ushort4*>(Ep + row * 512 + col * 4) =
              *reinterpret_cast<const ushort4*>(ov);
        }
      }
    }
  }
}

// ============ leaf_hc: vocab-level leaf activations Hl[v][128], Cl[v][128] ============
__global__ void leaf_hc(const u16* __restrict__ Ep,
                        u16* __restrict__ Hl, u16* __restrict__ Cl)
{
  const int tid = threadIdx.x;
  const int r = tid >> 6, c2 = tid & 63;           // 4 vocab rows/block, 2 cols/thread
  const size_t v = (size_t)blockIdx.x * 4 + r;     // grid = 12500 -> covers 50000 exactly
  uint4 g = *reinterpret_cast<const uint4*>(Ep + v * 512 + (size_t)c2 * 8);
  const u16* p = reinterpret_cast<const u16*>(&g); // {i,u,o,f} x 2 cols
  float c0 = sigmoidf_(bf2f(p[0])) * tanhf_(bf2f(p[1]));
  float c1 = sigmoidf_(bf2f(p[4])) * tanhf_(bf2f(p[5]));
  float h0 = sigmoidf_(bf2f(p[2])) * tanhf_(c0);
  float h1 = sigmoidf_(bf2f(p[6])) * tanhf_(c1);
  *reinterpret_cast<unsigned int*>(Hl + v * 128 + c2 * 2) = f2bf_pk(h0, h1);
  *reinterpret_cast<unsigned int*>(Cl + v * 128 + c2 * 2) = f2bf_pk(c0, c1);
}

// ============ k_l3fused v3: narrow h-side + Ep-epilogue x-side, then L3 step ============
// Per L4 node: Hl[vc] 256B + Cl[vc] 256B staged; x-side preacts come from Ep[vp] as
// 8-byte ushort4 epilogue reads (Ep already includes both biases). Phase 1 is h-side-only
// MFMA (same W_*h fragments as phase 2). No ldsX, no x-MFMA (R7's 66KB/2blk -> 48.6KB/3blk).
// Phase 1 epilogue: gates = act(hacc + Ep[vp]); c4 = i*u + f*cl (ldsC in place); h4 -> ldsA.
// Phase 2: L3 tree-LSTM step (identical to R6 back half).
__global__ __launch_bounds__(256, 2) void k_l3fused(
    const int* __restrict__ sen, const u16* __restrict__ Ep,
    const u16* __restrict__ Hl, const u16* __restrict__ Cl,
    const u16* __restrict__ BfT, const u16* __restrict__ BihT,
    const u16* __restrict__ BuhT, const u16* __restrict__ BohT,
    u16* __restrict__ c_out, u16* __restrict__ h_out,
    long o0, long o1, long o2)
{
  constexpr int PM = 32, CM = 64, NCI = 4, RT = 2;
  __shared__ __align__(16) u16 ldsH[CM * 128];   // leaf h (swz) 16 KB
  __shared__ __align__(16) u16 ldsC[CM * 128];   // leaf c -> L4 c in place (swz) 16 KB
  __shared__ __align__(16) u16 ldsA[CM * 128];   // L4 h (swz) 16 KB
  __shared__ int sidC[CM];                       // L4-node vocab ids
  __shared__ int sidP[PM];                       // L3-parent vocab ids

  const int tid = threadIdx.x;
  const long p0 = (long)blockIdx.x * PM;
  const long cb = (long)blockIdx.x * CM;

  // ---- phase 0: stage Hl/Cl (2 threads/row/table, 8 uint4 each -> high MLP) ----
  {
    const int r = (tid & 127) >> 1, half = tid & 1;
    const size_t vc = (size_t)sen[o2 + cb + r];   // leaf child's vocab id
    if (tid < 128) {
      const u16* hs = Hl + vc * 128;
#pragma unroll
      for (int ii = 0; ii < 8; ii++) {
        const int c16 = half * 8 + ii;
        *reinterpret_cast<uint4*>(&ldsH[swz128(r, c16)]) =
            *reinterpret_cast<const uint4*>(hs + c16 * 8);
      }
    } else {
      const u16* cs = Cl + vc * 128;
#pragma unroll
      for (int ii = 0; ii < 8; ii++) {
        const int c16 = half * 8 + ii;
        *reinterpret_cast<uint4*>(&ldsC[swz128(r, c16)]) =
            *reinterpret_cast<const uint4*>(cs + c16 * 8);
      }
    }
    if (tid < CM) sidC[tid] = sen[o1 + cb + tid];
    if (tid < PM) sidP[tid] = sen[o0 + p0 + tid];
  }
  __syncthreads();

  const int lane = tid & 63, w = tid >> 6, l16 = lane & 15, quad = lane >> 4;

  // ---- phase 1: L4 = act(Hl@W_*h + Ep[vp]) ; c4/h4 into LDS ----
#pragma unroll
  for (int gl = 0; gl < 2; gl++) {
    const int col = w * 32 + gl * 16 + l16;
    bf16x8 hI[4], hU[4], hO[4], hF[4];
#pragma unroll
    for (int ks = 0; ks < 4; ks++) {
      const size_t ho = (size_t)col * 128 + ks * 32 + quad * 8;
      hI[ks] = *reinterpret_cast<const bf16x8*>(BihT + ho);
      hU[ks] = *reinterpret_cast<const bf16x8*>(BuhT + ho);
      hO[ks] = *reinterpret_cast<const bf16x8*>(BohT + ho);
      hF[ks] = *reinterpret_cast<const bf16x8*>(BfT  + ho);
    }
#pragma unroll
    for (int i = 0; i < NCI; i++) {
      floatx4 aI = {0.f,0.f,0.f,0.f}, aU = {0.f,0.f,0.f,0.f};
      floatx4 aO = {0.f,0.f,0.f,0.f}, aF = {0.f,0.f,0.f,0.f};
#pragma unroll
      for (int ks = 0; ks < 4; ks++) {
        bf16x8 ah = *reinterpret_cast<const bf16x8*>(&ldsH[swz128(i * 16 + l16, ks * 4 + quad)]);
        aI = __builtin_amdgcn_mfma_f32_16x16x32_bf16(ah, hI[ks], aI, 0, 0, 0);
        aU = __builtin_amdgcn_mfma_f32_16x16x32_bf16(ah, hU[ks], aU, 0, 0, 0);
        aO = __builtin_amdgcn_mfma_f32_16x16x32_bf16(ah, hO[ks], aO, 0, 0, 0);
        aF = __builtin_amdgcn_mfma_f32_16x16x32_bf16(ah, hF[ks], aF, 0, 0, 0);
      }
      const int rbase = i * 16 + quad * 4;
#pragma unroll
      for (int r2 = 0; r2 < 4; r2++) {
        const int row = rbase + r2;
        // x-side preacts + biases from Ep (gate order {i,u,o,f})
        ushort4 e4 = *reinterpret_cast<const ushort4*>(
            Ep + (size_t)sidC[row] * 512 + col * 4);
        const float iv = sigmoidf_(aI[r2] + bf2f(e4.x));
        const float uv = tanhf_   (aU[r2] + bf2f(e4.y));
        const float ov = sigmoidf_(aO[r2] + bf2f(e4.z));
        const float fv = sigmoidf_(aF[r2] + bf2f(e4.w));
        const int sl = swze(row, col);
        const float c4 = fmaf(iv, uv, fv * bf2f(ldsC[sl]));
        const float h4 = ov * tanhf_(c4);
        ldsC[sl] = f2bf(c4);     // exclusive (row,col) ownership -> race-free in-place
        ldsA[sl] = f2bf(h4);
      }
    }
  }
  __syncthreads();

  // ---- phase 2: L3 tree-LSTM step (unchanged back half) ----
#pragma unroll
  for (int gl = 0; gl < 2; gl++) {
    const int col = w * 32 + gl * 16 + l16;
    bf16x8 bF[4], bI[4], bU[4], bO[4];
#pragma unroll
    for (int ks = 0; ks < 4; ks++) {
      const size_t bo_ = (size_t)col * 128 + ks * 32 + quad * 8;
      bF[ks] = *reinterpret_cast<const bf16x8*>(BfT + bo_);
      bI[ks] = *reinterpret_cast<const bf16x8*>(BihT + bo_);
      bU[ks] = *reinterpret_cast<const bf16x8*>(BuhT + bo_);
      bO[ks] = *reinterpret_cast<const bf16x8*>(BohT + bo_);
    }
#pragma unroll
    for (int i = 0; i < NCI; i++) {
      floatx4 aF = {0.f,0.f,0.f,0.f}, aI = {0.f,0.f,0.f,0.f};
      floatx4 aU = {0.f,0.f,0.f,0.f}, aO = {0.f,0.f,0.f,0.f};
#pragma unroll
      for (int ks = 0; ks < 4; ks++) {
        bf16x8 a = *reinterpret_cast<const bf16x8*>(&ldsA[swz128(i * 16 + l16, ks * 4 + quad)]);
        aF = __builtin_amdgcn_mfma_f32_16x16x32_bf16(a, bF[ks], aF, 0, 0, 0);
        aI = __builtin_amdgcn_mfma_f32_16x16x32_bf16(a, bI[ks], aI, 0, 0, 0);
        aU = __builtin_amdgcn_mfma_f32_16x16x32_bf16(a, bU[ks], aU, 0, 0, 0);
        aO = __builtin_amdgcn_mfma_f32_16x16x32_bf16(a, bO[ks], aO, 0, 0, 0);
      }
      const int rbase = i * 16 + quad * 4;
#pragma unroll
      for (int t = 0; t < 2; t++) {
        const int p = (rbase >> 1) + t;
        ushort4 g4 = *reinterpret_cast<const ushort4*>(Ep + (size_t)sidP[p] * 512 + col * 4);
        const float epf = bf2f(g4.w);
        float fsum = 0.f, isum = 0.f, usum = 0.f, osum = 0.f;
#pragma unroll
        for (int r2 = t * RT; r2 < t * RT + RT; r2++) {
          const int row = rbase + r2;
          const float cch = bf2f(ldsC[swze(row, col)]);
          fsum += sigmoidf_(aF[r2] + epf) * cch;
          isum += aI[r2]; usum += aU[r2]; osum += aO[r2];
        }
        const float c = sigmoidf_(isum + bf2f(g4.x)) * tanhf_(usum + bf2f(g4.y)) + fsum;
        const float h = sigmoidf_(osum + bf2f(g4.z)) * tanhf_(c);
        c_out[(p0 + p) * 128 + col] = f2bf(c);
        h_out[(p0 + p) * 128 + col] = f2bf(h);
      }
    }
  }
}

// ============ k_level: per-i-tile fused f/i/u/o (inner levels, computed children) ============
template<int LR>
__global__ __launch_bounds__(256, 2) void k_level(
    const int* __restrict__ sen, const u16* __restrict__ Ep,
    const u16* __restrict__ h_prev, const u16* __restrict__ c_prev,
    const u16* __restrict__ BfT, const u16* __restrict__ BihT,
    const u16* __restrict__ BuhT, const u16* __restrict__ BohT,
    u16* __restrict__ c_out, u16* __restrict__ h_out,
    long o0)
{
  constexpr int PM  = (LR == 2) ? 32 : 64;
  constexpr int CM  = PM << LR;
  constexpr int NCI = CM / 16;
  constexpr int RT  = 1 << LR;
  constexpr int RTI = 4 >> LR;         // parents per 4-row quad block
  constexpr int TPR = 256 / CM;        // staging threads per child row
  __shared__ __align__(16) u16 ldsA[CM * 128];   // child h (swz)
  __shared__ int sidP[PM];

  const int tid = threadIdx.x;
  const long p0 = (long)blockIdx.x * PM;
  const long cb = (long)blockIdx.x * CM;

  // ---- stage children ----
  {
    const int r = tid / TPR, q = tid % TPR;
    constexpr int CH = 16 / TPR;
    const u16* src = h_prev + (cb + r) * 128;
#pragma unroll
    for (int ii = 0; ii < CH; ii++) {
      const int c16 = q * CH + ii;
      *reinterpret_cast<uint4*>(&ldsA[swz128(r, c16)]) =
          *reinterpret_cast<const uint4*>(src + c16 * 8);
    }
    if (tid < PM) sidP[tid] = sen[o0 + p0 + tid];
  }
  __syncthreads();

  const int lane = tid & 63, w = tid >> 6, l16 = lane & 15, quad = lane >> 4;

#pragma unroll
  for (int gl = 0; gl < 2; gl++) {
    const int col = w * 32 + gl * 16 + l16;
    bf16x8 bF[4], bI[4], bU[4], bO[4];
#pragma unroll
    for (int ks = 0; ks < 4; ks++) {
      const size_t bo_ = (size_t)col * 128 + ks * 32 + quad * 8;
      bF[ks] = *reinterpret_cast<const bf16x8*>(BfT + bo_);
      bI[ks] = *reinterpret_cast<const bf16x8*>(BihT + bo_);
      bU[ks] = *reinterpret_cast<const bf16x8*>(BuhT + bo_);
      bO[ks] = *reinterpret_cast<const bf16x8*>(BohT + bo_);
    }
#pragma unroll
    for (int i = 0; i < NCI; i++) {
      floatx4 aF = {0.f,0.f,0.f,0.f}, aI = {0.f,0.f,0.f,0.f};
      floatx4 aU = {0.f,0.f,0.f,0.f}, aO = {0.f,0.f,0.f,0.f};
#pragma unroll
      for (int ks = 0; ks < 4; ks++) {
        bf16x8 a = *reinterpret_cast<const bf16x8*>(&ldsA[swz128(i * 16 + l16, ks * 4 + quad)]);
        aF = __builtin_amdgcn_mfma_f32_16x16x32_bf16(a, bF[ks], aF, 0, 0, 0);
        aI = __builtin_amdgcn_mfma_f32_16x16x32_bf16(a, bI[ks], aI, 0, 0, 0);
        aU = __builtin_amdgcn_mfma_f32_16x16x32_bf16(a, bU[ks], aU, 0, 0, 0);
        aO = __builtin_amdgcn_mfma_f32_16x16x32_bf16(a, bO[ks], aO, 0, 0, 0);
      }
      const int rbase = i * 16 + quad * 4;
#pragma unroll
      for (int t = 0; t < RTI; t++) {
        const int p = (rbase >> LR) + t;
        ushort4 g4 = *reinterpret_cast<const ushort4*>(Ep + (size_t)sidP[p] * 512 + col * 4);
        const float epf = bf2f(g4.w);
        float fsum = 0.f, isum = 0.f, usum = 0.f, osum = 0.f;
#pragma unroll
        for (int r2 = t * RT; r2 < t * RT + RT; r2++) {
          const int row = rbase + r2;
          const float cch = bf2f(c_prev[(cb + row) * 128 + col]);
          fsum += sigmoidf_(aF[r2] + epf) * cch;
          isum += aI[r2]; usum += aU[r2]; osum += aO[r2];
        }
        const float c = sigmoidf_(isum + bf2f(g4.x)) * tanhf_(usum + bf2f(g4.y)) + fsum;
        const float h = sigmoidf_(osum + bf2f(g4.z)) * tanhf_(c);
        c_out[(p0 + p) * 128 + col] = f2bf(c);
        h_out[(p0 + p) * 128 + col] = f2bf(h);
      }
    }
  }
}

// ---------- weight/bias prep ----------
__global__ void build_wallT(const float* __restrict__ Wix, const float* __restrict__ Wux,
                            const float* __restrict__ Wox, const float* __restrict__ Wfx,
                            u16* __restrict__ WT)
{
  int idx = blockIdx.x * 256 + threadIdx.x;   // 512*128
  int n = idx >> 7, k = idx & 127;
  int g = n >> 7, j = n & 127;
  const float* W = (g == 0) ? Wix : (g == 1) ? Wux : (g == 2) ? Wox : Wfx;
  WT[idx] = f2bf(W[k * 128 + j]);
}

__global__ void build_bsum(const float* __restrict__ b_ix, const float* __restrict__ b_ih,
                           const float* __restrict__ b_ux, const float* __restrict__ b_uh,
                           const float* __restrict__ b_ox, const float* __restrict__ b_oh,
                           const float* __restrict__ b_fx, const float* __restrict__ b_fh,
                           float* __restrict__ bsum)
{
  int n = blockIdx.x * 256 + threadIdx.x;   // 512
  int g = n >> 7, j = n & 127;
  float v = (g == 0) ? b_ix[j] + b_ih[j] : (g == 1) ? b_ux[j] + b_uh[j]
          : (g == 2) ? b_ox[j] + b_oh[j] : b_fx[j] + b_fh[j];
  bsum[n] = v;
}

__global__ void build_bt128(const float* __restrict__ W, u16* __restrict__ BT) {
  int idx = blockIdx.x * 256 + threadIdx.x;   // 128*128
  int n = idx >> 7, k = idx & 127;
  BT[idx] = f2bf(W[k * 128 + n]);
}

// ---------- output projection (4096 x 4, tiny) ----------
__global__ void out_proj(const u16* __restrict__ h_root, const float* __restrict__ W_out,
                         const float* __restrict__ b_out, float* __restrict__ out)
{
  int idx = blockIdx.x * 256 + threadIdx.x;   // 4096*4
  int n = idx >> 2, cls = idx & 3;
  float s = b_out[cls];
  for (int k = 0; k < 128; k++)
    s += bf2f(h_root[(long)n * 128 + k]) * W_out[k * 4 + cls];
  out[idx] = s;
}

extern "C" void kernel_launch(void* const* d_in, const int* in_sizes, int n_in,
                              void* d_out, int out_size, void* d_ws, size_t ws_size,
                              hipStream_t stream)
{
  const int*   sen  = (const int*)d_in[0];
  const float* emb  = (const float*)d_in[1];
  const float* W_ix = (const float*)d_in[2];  const float* b_ix = (const float*)d_in[3];
  const float* W_ih = (const float*)d_in[4];  const float* b_ih = (const float*)d_in[5];
  const float* W_fx = (const float*)d_in[6];  const float* b_fx = (const float*)d_in[7];
  const float* W_fh = (const float*)d_in[8];  const float* b_fh = (const float*)d_in[9];
  const float* W_ox = (const float*)d_in[10]; const float* b_ox = (const float*)d_in[11];
  const float* W_oh = (const float*)d_in[12]; const float* b_oh = (const float*)d_in[13];
  const float* W_ux = (const float*)d_in[14]; const float* b_ux = (const float*)d_in[15];
  const float* W_uh = (const float*)d_in[16]; const float* b_uh = (const float*)d_in[17];
  const float* W_out= (const float*)d_in[18]; const float* b_out= (const float*)d_in[19];
  float* out = (float*)d_out;

  // ---- workspace ----
  const size_t EPB = (size_t)50000 * 512 * 2;       // Ep (51.2 MB)
  const size_t TBB = (size_t)50000 * 128 * 2;       // Hl / Cl (12.8 MB each)
  const size_t H3  = (size_t)131072 * 128 * 2;      // 33.55 MB each
  const size_t H2  = (size_t)65536  * 128 * 2;
  const size_t H1  = (size_t)16384  * 128 * 2;
  const size_t H0  = (size_t)4096   * 128 * 2;
  const size_t need = EPB + 2 * TBB + 2 * (H3 + H2 + H1 + H0)
                    + (size_t)512 * 128 * 2 + 4 * (size_t)128 * 128 * 2 + 512 * 4 + 8192;
  fprintf(stderr, "[tree_lstm] ws_size=%zu need=%zu\n", ws_size, need);
  if (ws_size < need) {
    fprintf(stderr, "[tree_lstm] INSUFFICIENT WORKSPACE — skipping launch\n");
    return;
  }
  char* ws = (char*)d_ws;
  size_t off = 0;
  auto take = [&](size_t bytes) { char* p = ws + off; off += (bytes + 255) & ~(size_t)255; return p; };
  u16* Ep = (u16*)take(EPB);
  u16* Hl = (u16*)take(TBB);
  u16* Cl = (u16*)take(TBB);
  u16* h3 = (u16*)take(H3);  u16* c3 = (u16*)take(H3);
  u16* h2 = (u16*)take(H2);  u16* c2 = (u16*)take(H2);
  u16* h1 = (u16*)take(H1);  u16* c1 = (u16*)take(H1);
  u16* h0 = (u16*)take(H0);  u16* c0 = (u16*)take(H0);
  u16* WallT = (u16*)take((size_t)512 * 128 * 2);
  u16* BihT = (u16*)take((size_t)128 * 128 * 2);
  u16* BuhT = (u16*)take((size_t)128 * 128 * 2);
  u16* BohT = (u16*)take((size_t)128 * 128 * 2);
  u16* BfhT = (u16*)take((size_t)128 * 128 * 2);
  float* bsum = (float*)take(512 * 4);

  // ---- prep ----
  build_wallT<<<256, 256, 0, stream>>>(W_ix, W_ux, W_ox, W_fx, WallT);
  build_bsum<<<2, 256, 0, stream>>>(b_ix, b_ih, b_ux, b_uh, b_ox, b_oh, b_fx, b_fh, bsum);
  build_bt128<<<64, 256, 0, stream>>>(W_ih, BihT);
  build_bt128<<<64, 256, 0, stream>>>(W_uh, BuhT);
  build_bt128<<<64, 256, 0, stream>>>(W_oh, BohT);
  build_bt128<<<64, 256, 0, stream>>>(W_fh, BfhT);
  proj_e<<<391, 256, 0, stream>>>(emb, WallT, bsum, Ep);
  leaf_hc<<<12500, 256, 0, stream>>>(Ep, Hl, Cl);

  const long LOFF[6] = {0, 4096, 20480, 86016, 217088, 479232};

  // L3 (131072 parents) with L4 computed in-kernel (h-side MFMA + Ep-epilogue x-side)
  k_l3fused<<<4096, 256, 0, stream>>>(sen, Ep, Hl, Cl,
      BfhT, BihT, BuhT, BohT, c3, h3, LOFF[3], LOFF[4], LOFF[5]);
  // L2 (65536, ratio 2)
  k_level<1><<<1024, 256, 0, stream>>>(sen, Ep, h3, c3,
      BfhT, BihT, BuhT, BohT, c2, h2, LOFF[2]);
  // L1 (16384, ratio 4)
  k_level<2><<<512, 256, 0, stream>>>(sen, Ep, h2, c2,
      BfhT, BihT, BuhT, BohT, c1, h1, LOFF[1]);
  // L0 (4096, ratio 4)
  k_level<2><<<128, 256, 0, stream>>>(sen, Ep, h1, c1,
      BfhT, BihT, BuhT, BohT, c0, h0, LOFF[0]);

  out_proj<<<64, 256, 0, stream>>>(h0, W_out, b_out, out);
}

// Round 9
// 494.218 us; speedup vs baseline: 1.4189x; 1.0559x over previous
//
#include <hip/hip_runtime.h>
#include <hip/hip_bf16.h>
#include <cstdio>

typedef unsigned short u16;
typedef __bf16 bf16x8 __attribute__((ext_vector_type(8)));
typedef float  floatx4 __attribute__((ext_vector_type(4)));

// ---------- scalar helpers ----------
__device__ __forceinline__ float bf2f(u16 u) {
  union { unsigned int i; float f; } v; v.i = ((unsigned int)u) << 16; return v.f;
}
__device__ __forceinline__ u16 f2bf(float f) {
  union { float f; unsigned int i; } v; v.f = f;
  unsigned int x = v.i;
  return (u16)((x + 0x7fffu + ((x >> 16) & 1u)) >> 16);   // RNE
}
__device__ __forceinline__ unsigned int f2bf_pk(float a, float b) {   // [lo=a, hi=b]
  __hip_bfloat162 h = __float22bfloat162_rn(make_float2(a, b));
  union { __hip_bfloat162 h; unsigned int u; } v; v.h = h; return v.u;
}
// fast gates: v_rcp (~1 ulp) + native exp — no IEEE div
__device__ __forceinline__ float sigmoidf_(float x) {
  return __builtin_amdgcn_rcpf(1.f + __expf(-x));
}
__device__ __forceinline__ float tanhf_(float x) {
  return fmaf(-2.f, __builtin_amdgcn_rcpf(1.f + __expf(2.f * x)), 1.f);
}

// LDS swizzle, 128-elem rows, 16B chunks: chunk' = chunk ^ (row&15)
__device__ __forceinline__ int swz128(int row, int c16) {
  return row * 128 + ((c16 ^ (row & 15)) << 3);
}
// element-level access into swizzled rows
__device__ __forceinline__ int swze(int row, int col) {
  return row * 128 + (((((col >> 3)) ^ (row & 15)) << 3) | (col & 7));
}

// ============ proj_e: Ep[v][col][4] = {i,u,o,f} pre-acts + biases (gate-interleaved) ============
__global__ __launch_bounds__(256, 2) void proj_e(
    const float* __restrict__ emb, const u16* __restrict__ WT,
    const float* __restrict__ bsum, u16* __restrict__ Ep)
{
  __shared__ __align__(16) u16 ldsA[128 * 128];
  const int tid = threadIdx.x;
  const long m0 = (long)blockIdx.x * 128;
  {
    const int r = tid >> 1, half = tid & 1;
    long row = m0 + r; if (row > 49999) row = 49999;
    const float* src = emb + row * 128 + half * 64;
#pragma unroll
    for (int i = 0; i < 8; i++) {
      float4 v0 = *reinterpret_cast<const float4*>(src + i * 8);
      float4 v1 = *reinterpret_cast<const float4*>(src + i * 8 + 4);
      unsigned int ov[4] = { f2bf_pk(v0.x, v0.y), f2bf_pk(v0.z, v0.w),
                             f2bf_pk(v1.x, v1.y), f2bf_pk(v1.z, v1.w) };
      *reinterpret_cast<uint4*>(&ldsA[swz128(r, half * 8 + i)]) =
          *reinterpret_cast<const uint4*>(ov);
    }
  }
  __syncthreads();
  const int lane = tid & 63, w = tid >> 6, l16 = lane & 15, quad = lane >> 4;
#pragma unroll
  for (int half = 0; half < 2; half++) {
    const int col = w * 32 + half * 16 + l16;
    bf16x8 bI[4], bU[4], bO[4], bF[4];
#pragma unroll
    for (int ks = 0; ks < 4; ks++) {
      const size_t o_ = ks * 32 + quad * 8;
      bI[ks] = *reinterpret_cast<const bf16x8*>(WT + (size_t)(0   + col) * 128 + o_);
      bU[ks] = *reinterpret_cast<const bf16x8*>(WT + (size_t)(128 + col) * 128 + o_);
      bO[ks] = *reinterpret_cast<const bf16x8*>(WT + (size_t)(256 + col) * 128 + o_);
      bF[ks] = *reinterpret_cast<const bf16x8*>(WT + (size_t)(384 + col) * 128 + o_);
    }
    const float bi = bsum[col], bu = bsum[128 + col], bo = bsum[256 + col], bf = bsum[384 + col];
#pragma unroll
    for (int i = 0; i < 8; i++) {
      floatx4 aI = {0.f,0.f,0.f,0.f}, aU = {0.f,0.f,0.f,0.f};
      floatx4 aO = {0.f,0.f,0.f,0.f}, aF = {0.f,0.f,0.f,0.f};
#pragma unroll
      for (int ks = 0; ks < 4; ks++) {
        bf16x8 a = *reinterpret_cast<const bf16x8*>(&ldsA[swz128(i * 16 + l16, ks * 4 + quad)]);
        aI = __builtin_amdgcn_mfma_f32_16x16x32_bf16(a, bI[ks], aI, 0, 0, 0);
        aU = __builtin_amdgcn_mfma_f32_16x16x32_bf16(a, bU[ks], aU, 0, 0, 0);
        aO = __builtin_amdgcn_mfma_f32_16x16x32_bf16(a, bO[ks], aO, 0, 0, 0);
        aF = __builtin_amdgcn_mfma_f32_16x16x32_bf16(a, bF[ks], aF, 0, 0, 0);
      }
#pragma unroll
      for (int r2 = 0; r2 < 4; r2++) {
        const long row = m0 + i * 16 + quad * 4 + r2;
        if (row < 50000) {
          u16 ov[4] = { f2bf(aI[r2] + bi), f2bf(aU[r2] + bu),
                        f2bf(aO[r2] + bo), f2bf(aF[r2] + bf) };
          *reinterpret_cast<ushort4*>(Ep + row * 512 + col * 4) =
              *reinterpret_cast<const ushort4*>(ov);
        }
      }
    }
  }
}

// ============ leaf_hc: vocab-level leaf activations Hl[v][128], Cl[v][128] ============
__global__ void leaf_hc(const u16* __restrict__ Ep,
                        u16* __restrict__ Hl, u16* __restrict__ Cl)
{
  const int tid = threadIdx.x;
  const int r = tid >> 6, c2 = tid & 63;           // 4 vocab rows/block, 2 cols/thread
  const size_t v = (size_t)blockIdx.x * 4 + r;     // grid = 12500 -> covers 50000 exactly
  uint4 g = *reinterpret_cast<const uint4*>(Ep + v * 512 + (size_t)c2 * 8);
  const u16* p = reinterpret_cast<const u16*>(&g); // {i,u,o,f} x 2 cols
  float c0 = sigmoidf_(bf2f(p[0])) * tanhf_(bf2f(p[1]));
  float c1 = sigmoidf_(bf2f(p[4])) * tanhf_(bf2f(p[5]));
  float h0 = sigmoidf_(bf2f(p[2])) * tanhf_(c0);
  float h1 = sigmoidf_(bf2f(p[6])) * tanhf_(c1);
  *reinterpret_cast<unsigned int*>(Hl + v * 128 + c2 * 2) = f2bf_pk(h0, h1);
  *reinterpret_cast<unsigned int*>(Cl + v * 128 + c2 * 2) = f2bf_pk(c0, c1);
}

// ============ k_l3fused v4: v3 + batched register prefetch of all epilogue gathers ============
// The v3 limiter (R8 counters: HBM 16%, MFMA 11%, VALU 37%, occ 23% — nothing saturated)
// is dependent L2-miss latency on the per-(row,col) Ep reads issued inside the epilogues.
// v4 front-loads them: per gl, ALL 16 phase-1 e4 reads (and all 8 phase-2 g4 reads) issue
// into registers before weights+MFMAs -> 16 outstanding misses/wave instead of 4, hidden
// under the MFMA+activation work. Bit-identical values, pure reorder.
// launch_bounds(256,3): LDS (48.6KB) caps at 3 blocks/CU anyway; this sets the VGPR budget
// to ~170 so the +32 prefetch regs can't push past the 168-VGPR occupancy cliff (and the
// budget is far above the ~150 needed, so no R5-style forced spill).
__global__ __launch_bounds__(256, 3) void k_l3fused(
    const int* __restrict__ sen, const u16* __restrict__ Ep,
    const u16* __restrict__ Hl, const u16* __restrict__ Cl,
    const u16* __restrict__ BfT, const u16* __restrict__ BihT,
    const u16* __restrict__ BuhT, const u16* __restrict__ BohT,
    u16* __restrict__ c_out, u16* __restrict__ h_out,
    long o0, long o1, long o2)
{
  constexpr int PM = 32, CM = 64, NCI = 4, RT = 2;
  __shared__ __align__(16) u16 ldsH[CM * 128];   // leaf h (swz) 16 KB
  __shared__ __align__(16) u16 ldsC[CM * 128];   // leaf c -> L4 c in place (swz) 16 KB
  __shared__ __align__(16) u16 ldsA[CM * 128];   // L4 h (swz) 16 KB
  __shared__ int sidC[CM];                       // L4-node vocab ids
  __shared__ int sidP[PM];                       // L3-parent vocab ids

  const int tid = threadIdx.x;
  const long p0 = (long)blockIdx.x * PM;
  const long cb = (long)blockIdx.x * CM;

  // ---- phase 0: stage Hl/Cl (2 threads/row/table, 8 uint4 each -> high MLP) ----
  {
    const int r = (tid & 127) >> 1, half = tid & 1;
    const size_t vc = (size_t)sen[o2 + cb + r];   // leaf child's vocab id
    if (tid < 128) {
      const u16* hs = Hl + vc * 128;
#pragma unroll
      for (int ii = 0; ii < 8; ii++) {
        const int c16 = half * 8 + ii;
        *reinterpret_cast<uint4*>(&ldsH[swz128(r, c16)]) =
            *reinterpret_cast<const uint4*>(hs + c16 * 8);
      }
    } else {
      const u16* cs = Cl + vc * 128;
#pragma unroll
      for (int ii = 0; ii < 8; ii++) {
        const int c16 = half * 8 + ii;
        *reinterpret_cast<uint4*>(&ldsC[swz128(r, c16)]) =
            *reinterpret_cast<const uint4*>(cs + c16 * 8);
      }
    }
    if (tid < CM) sidC[tid] = sen[o1 + cb + tid];
    if (tid < PM) sidP[tid] = sen[o0 + p0 + tid];
  }
  __syncthreads();

  const int lane = tid & 63, w = tid >> 6, l16 = lane & 15, quad = lane >> 4;

  // ---- phase 1: L4 = act(Hl@W_*h + Ep[vp]) ; c4/h4 into LDS ----
#pragma unroll
  for (int gl = 0; gl < 2; gl++) {
    const int col = w * 32 + gl * 16 + l16;
    // batched prefetch: all 16 x-side preact reads for this gl, issued up front
    ushort4 e4p[NCI][4];
#pragma unroll
    for (int i = 0; i < NCI; i++) {
      const int rbase = i * 16 + quad * 4;
#pragma unroll
      for (int r2 = 0; r2 < 4; r2++)
        e4p[i][r2] = *reinterpret_cast<const ushort4*>(
            Ep + (size_t)sidC[rbase + r2] * 512 + col * 4);
    }
    bf16x8 hI[4], hU[4], hO[4], hF[4];
#pragma unroll
    for (int ks = 0; ks < 4; ks++) {
      const size_t ho = (size_t)col * 128 + ks * 32 + quad * 8;
      hI[ks] = *reinterpret_cast<const bf16x8*>(BihT + ho);
      hU[ks] = *reinterpret_cast<const bf16x8*>(BuhT + ho);
      hO[ks] = *reinterpret_cast<const bf16x8*>(BohT + ho);
      hF[ks] = *reinterpret_cast<const bf16x8*>(BfT  + ho);
    }
#pragma unroll
    for (int i = 0; i < NCI; i++) {
      floatx4 aI = {0.f,0.f,0.f,0.f}, aU = {0.f,0.f,0.f,0.f};
      floatx4 aO = {0.f,0.f,0.f,0.f}, aF = {0.f,0.f,0.f,0.f};
#pragma unroll
      for (int ks = 0; ks < 4; ks++) {
        bf16x8 ah = *reinterpret_cast<const bf16x8*>(&ldsH[swz128(i * 16 + l16, ks * 4 + quad)]);
        aI = __builtin_amdgcn_mfma_f32_16x16x32_bf16(ah, hI[ks], aI, 0, 0, 0);
        aU = __builtin_amdgcn_mfma_f32_16x16x32_bf16(ah, hU[ks], aU, 0, 0, 0);
        aO = __builtin_amdgcn_mfma_f32_16x16x32_bf16(ah, hO[ks], aO, 0, 0, 0);
        aF = __builtin_amdgcn_mfma_f32_16x16x32_bf16(ah, hF[ks], aF, 0, 0, 0);
      }
      const int rbase = i * 16 + quad * 4;
#pragma unroll
      for (int r2 = 0; r2 < 4; r2++) {
        const int row = rbase + r2;
        const ushort4 e4 = e4p[i][r2];   // prefetched {i,u,o,f}
        const float iv = sigmoidf_(aI[r2] + bf2f(e4.x));
        const float uv = tanhf_   (aU[r2] + bf2f(e4.y));
        const float ov = sigmoidf_(aO[r2] + bf2f(e4.z));
        const float fv = sigmoidf_(aF[r2] + bf2f(e4.w));
        const int sl = swze(row, col);
        const float c4 = fmaf(iv, uv, fv * bf2f(ldsC[sl]));
        const float h4 = ov * tanhf_(c4);
        ldsC[sl] = f2bf(c4);     // exclusive (row,col) ownership -> race-free in-place
        ldsA[sl] = f2bf(h4);
      }
    }
  }
  __syncthreads();

  // ---- phase 2: L3 tree-LSTM step ----
#pragma unroll
  for (int gl = 0; gl < 2; gl++) {
    const int col = w * 32 + gl * 16 + l16;
    // batched prefetch: all 8 parent preact reads for this gl
    ushort4 g4p[NCI][2];
#pragma unroll
    for (int i = 0; i < NCI; i++) {
      const int rbase = i * 16 + quad * 4;
#pragma unroll
      for (int t = 0; t < 2; t++)
        g4p[i][t] = *reinterpret_cast<const ushort4*>(
            Ep + (size_t)sidP[(rbase >> 1) + t] * 512 + col * 4);
    }
    bf16x8 bF[4], bI[4], bU[4], bO[4];
#pragma unroll
    for (int ks = 0; ks < 4; ks++) {
      const size_t bo_ = (size_t)col * 128 + ks * 32 + quad * 8;
      bF[ks] = *reinterpret_cast<const bf16x8*>(BfT + bo_);
      bI[ks] = *reinterpret_cast<const bf16x8*>(BihT + bo_);
      bU[ks] = *reinterpret_cast<const bf16x8*>(BuhT + bo_);
      bO[ks] = *reinterpret_cast<const bf16x8*>(BohT + bo_);
    }
#pragma unroll
    for (int i = 0; i < NCI; i++) {
      floatx4 aF = {0.f,0.f,0.f,0.f}, aI = {0.f,0.f,0.f,0.f};
      floatx4 aU = {0.f,0.f,0.f,0.f}, aO = {0.f,0.f,0.f,0.f};
#pragma unroll
      for (int ks = 0; ks < 4; ks++) {
        bf16x8 a = *reinterpret_cast<const bf16x8*>(&ldsA[swz128(i * 16 + l16, ks * 4 + quad)]);
        aF = __builtin_amdgcn_mfma_f32_16x16x32_bf16(a, bF[ks], aF, 0, 0, 0);
        aI = __builtin_amdgcn_mfma_f32_16x16x32_bf16(a, bI[ks], aI, 0, 0, 0);
        aU = __builtin_amdgcn_mfma_f32_16x16x32_bf16(a, bU[ks], aU, 0, 0, 0);
        aO = __builtin_amdgcn_mfma_f32_16x16x32_bf16(a, bO[ks], aO, 0, 0, 0);
      }
      const int rbase = i * 16 + quad * 4;
#pragma unroll
      for (int t = 0; t < 2; t++) {
        const int p = (rbase >> 1) + t;
        const ushort4 g4 = g4p[i][t];
        const float epf = bf2f(g4.w);
        float fsum = 0.f, isum = 0.f, usum = 0.f, osum = 0.f;
#pragma unroll
        for (int r2 = t * RT; r2 < t * RT + RT; r2++) {
          const int row = rbase + r2;
          const float cch = bf2f(ldsC[swze(row, col)]);
          fsum += sigmoidf_(aF[r2] + epf) * cch;
          isum += aI[r2]; usum += aU[r2]; osum += aO[r2];
        }
        const float c = sigmoidf_(isum + bf2f(g4.x)) * tanhf_(usum + bf2f(g4.y)) + fsum;
        const float h = sigmoidf_(osum + bf2f(g4.z)) * tanhf_(c);
        c_out[(p0 + p) * 128 + col] = f2bf(c);
        h_out[(p0 + p) * 128 + col] = f2bf(h);
      }
    }
  }
}

// ============ k_level: per-i-tile fused f/i/u/o (inner levels, computed children) ============
// Epilogue operands (g4 from Ep, cch from c_prev) prefetched at the top of each i-iter
// so the loads overlap the 16 MFMAs instead of stalling the epilogue.
template<int LR>
__global__ __launch_bounds__(256, 2) void k_level(
    const int* __restrict__ sen, const u16* __restrict__ Ep,
    const u16* __restrict__ h_prev, const u16* __restrict__ c_prev,
    const u16* __restrict__ BfT, const u16* __restrict__ BihT,
    const u16* __restrict__ BuhT, const u16* __restrict__ BohT,
    u16* __restrict__ c_out, u16* __restrict__ h_out,
    long o0)
{
  constexpr int PM  = (LR == 2) ? 32 : 64;
  constexpr int CM  = PM << LR;
  constexpr int NCI = CM / 16;
  constexpr int RT  = 1 << LR;
  constexpr int RTI = 4 >> LR;         // parents per 4-row quad block
  constexpr int TPR = 256 / CM;        // staging threads per child row
  __shared__ __align__(16) u16 ldsA[CM * 128];   // child h (swz)
  __shared__ int sidP[PM];

  const int tid = threadIdx.x;
  const long p0 = (long)blockIdx.x * PM;
  const long cb = (long)blockIdx.x * CM;

  // ---- stage children ----
  {
    const int r = tid / TPR, q = tid % TPR;
    constexpr int CH = 16 / TPR;
    const u16* src = h_prev + (cb + r) * 128;
#pragma unroll
    for (int ii = 0; ii < CH; ii++) {
      const int c16 = q * CH + ii;
      *reinterpret_cast<uint4*>(&ldsA[swz128(r, c16)]) =
          *reinterpret_cast<const uint4*>(src + c16 * 8);
    }
    if (tid < PM) sidP[tid] = sen[o0 + p0 + tid];
  }
  __syncthreads();

  const int lane = tid & 63, w = tid >> 6, l16 = lane & 15, quad = lane >> 4;

#pragma unroll
  for (int gl = 0; gl < 2; gl++) {
    const int col = w * 32 + gl * 16 + l16;
    bf16x8 bF[4], bI[4], bU[4], bO[4];
#pragma unroll
    for (int ks = 0; ks < 4; ks++) {
      const size_t bo_ = (size_t)col * 128 + ks * 32 + quad * 8;
      bF[ks] = *reinterpret_cast<const bf16x8*>(BfT + bo_);
      bI[ks] = *reinterpret_cast<const bf16x8*>(BihT + bo_);
      bU[ks] = *reinterpret_cast<const bf16x8*>(BuhT + bo_);
      bO[ks] = *reinterpret_cast<const bf16x8*>(BohT + bo_);
    }
#pragma unroll
    for (int i = 0; i < NCI; i++) {
      const int rbase = i * 16 + quad * 4;
      // prefetch epilogue operands before the MFMA chain
      ushort4 g4p[RTI];
      u16 cch16[RTI][RT];
#pragma unroll
      for (int t = 0; t < RTI; t++) {
        g4p[t] = *reinterpret_cast<const ushort4*>(
            Ep + (size_t)sidP[(rbase >> LR) + t] * 512 + col * 4);
#pragma unroll
        for (int r2 = 0; r2 < RT; r2++)
          cch16[t][r2] = c_prev[(cb + rbase + t * RT + r2) * 128 + col];
      }
      floatx4 aF = {0.f,0.f,0.f,0.f}, aI = {0.f,0.f,0.f,0.f};
      floatx4 aU = {0.f,0.f,0.f,0.f}, aO = {0.f,0.f,0.f,0.f};
#pragma unroll
      for (int ks = 0; ks < 4; ks++) {
        bf16x8 a = *reinterpret_cast<const bf16x8*>(&ldsA[swz128(i * 16 + l16, ks * 4 + quad)]);
        aF = __builtin_amdgcn_mfma_f32_16x16x32_bf16(a, bF[ks], aF, 0, 0, 0);
        aI = __builtin_amdgcn_mfma_f32_16x16x32_bf16(a, bI[ks], aI, 0, 0, 0);
        aU = __builtin_amdgcn_mfma_f32_16x16x32_bf16(a, bU[ks], aU, 0, 0, 0);
        aO = __builtin_amdgcn_mfma_f32_16x16x32_bf16(a, bO[ks], aO, 0, 0, 0);
      }
#pragma unroll
      for (int t = 0; t < RTI; t++) {
        const int p = (rbase >> LR) + t;
        const ushort4 g4 = g4p[t];
        const float epf = bf2f(g4.w);
        float fsum = 0.f, isum = 0.f, usum = 0.f, osum = 0.f;
#pragma unroll
        for (int r2 = t * RT; r2 < t * RT + RT; r2++) {
          const float cch = bf2f(cch16[t][r2 - t * RT]);
          fsum += sigmoidf_(aF[r2] + epf) * cch;
          isum += aI[r2]; usum += aU[r2]; osum += aO[r2];
        }
        const float c = sigmoidf_(isum + bf2f(g4.x)) * tanhf_(usum + bf2f(g4.y)) + fsum;
        const float h = sigmoidf_(osum + bf2f(g4.z)) * tanhf_(c);
        c_out[(p0 + p) * 128 + col] = f2bf(c);
        h_out[(p0 + p) * 128 + col] = f2bf(h);
      }
    }
  }
}

// ---------- weight/bias prep ----------
__global__ void build_wallT(const float* __restrict__ Wix, const float* __restrict__ Wux,
                            const float* __restrict__ Wox, const float* __restrict__ Wfx,
                            u16* __restrict__ WT)
{
  int idx = blockIdx.x * 256 + threadIdx.x;   // 512*128
  int n = idx >> 7, k = idx & 127;
  int g = n >> 7, j = n & 127;
  const float* W = (g == 0) ? Wix : (g == 1) ? Wux : (g == 2) ? Wox : Wfx;
  WT[idx] = f2bf(W[k * 128 + j]);
}

__global__ void build_bsum(const float* __restrict__ b_ix, const float* __restrict__ b_ih,
                           const float* __restrict__ b_ux, const float* __restrict__ b_uh,
                           const float* __restrict__ b_ox, const float* __restrict__ b_oh,
                           const float* __restrict__ b_fx, const float* __restrict__ b_fh,
                           float* __restrict__ bsum)
{
  int n = blockIdx.x * 256 + threadIdx.x;   // 512
  int g = n >> 7, j = n & 127;
  float v = (g == 0) ? b_ix[j] + b_ih[j] : (g == 1) ? b_ux[j] + b_uh[j]
          : (g == 2) ? b_ox[j] + b_oh[j] : b_fx[j] + b_fh[j];
  bsum[n] = v;
}

__global__ void build_bt128(const float* __restrict__ W, u16* __restrict__ BT) {
  int idx = blockIdx.x * 256 + threadIdx.x;   // 128*128
  int n = idx >> 7, k = idx & 127;
  BT[idx] = f2bf(W[k * 128 + n]);
}

// ---------- output projection (4096 x 4, tiny) ----------
__global__ void out_proj(const u16* __restrict__ h_root, const float* __restrict__ W_out,
                         const float* __restrict__ b_out, float* __restrict__ out)
{
  int idx = blockIdx.x * 256 + threadIdx.x;   // 4096*4
  int n = idx >> 2, cls = idx & 3;
  float s = b_out[cls];
  for (int k = 0; k < 128; k++)
    s += bf2f(h_root[(long)n * 128 + k]) * W_out[k * 4 + cls];
  out[idx] = s;
}

extern "C" void kernel_launch(void* const* d_in, const int* in_sizes, int n_in,
                              void* d_out, int out_size, void* d_ws, size_t ws_size,
                              hipStream_t stream)
{
  const int*   sen  = (const int*)d_in[0];
  const float* emb  = (const float*)d_in[1];
  const float* W_ix = (const float*)d_in[2];  const float* b_ix = (const float*)d_in[3];
  const float* W_ih = (const float*)d_in[4];  const float* b_ih = (const float*)d_in[5];
  const float* W_fx = (const float*)d_in[6];  const float* b_fx = (const float*)d_in[7];
  const float* W_fh = (const float*)d_in[8];  const float* b_fh = (const float*)d_in[9];
  const float* W_ox = (const float*)d_in[10]; const float* b_ox = (const float*)d_in[11];
  const float* W_oh = (const float*)d_in[12]; const float* b_oh = (const float*)d_in[13];
  const float* W_ux = (const float*)d_in[14]; const float* b_ux = (const float*)d_in[15];
  const float* W_uh = (const float*)d_in[16]; const float* b_uh = (const float*)d_in[17];
  const float* W_out= (const float*)d_in[18]; const float* b_out= (const float*)d_in[19];
  float* out = (float*)d_out;

  // ---- workspace ----
  const size_t EPB = (size_t)50000 * 512 * 2;       // Ep (51.2 MB)
  const size_t TBB = (size_t)50000 * 128 * 2;       // Hl / Cl (12.8 MB each)
  const size_t H3  = (size_t)131072 * 128 * 2;      // 33.55 MB each
  const size_t H2  = (size_t)65536  * 128 * 2;
  const size_t H1  = (size_t)16384  * 128 * 2;
  const size_t H0  = (size_t)4096   * 128 * 2;
  const size_t need = EPB + 2 * TBB + 2 * (H3 + H2 + H1 + H0)
                    + (size_t)512 * 128 * 2 + 4 * (size_t)128 * 128 * 2 + 512 * 4 + 8192;
  fprintf(stderr, "[tree_lstm] ws_size=%zu need=%zu\n", ws_size, need);
  if (ws_size < need) {
    fprintf(stderr, "[tree_lstm] INSUFFICIENT WORKSPACE — skipping launch\n");
    return;
  }
  char* ws = (char*)d_ws;
  size_t off = 0;
  auto take = [&](size_t bytes) { char* p = ws + off; off += (bytes + 255) & ~(size_t)255; return p; };
  u16* Ep = (u16*)take(EPB);
  u16* Hl = (u16*)take(TBB);
  u16* Cl = (u16*)take(TBB);
  u16* h3 = (u16*)take(H3);  u16* c3 = (u16*)take(H3);
  u16* h2 = (u16*)take(H2);  u16* c2 = (u16*)take(H2);
  u16* h1 = (u16*)take(H1);  u16* c1 = (u16*)take(H1);
  u16* h0 = (u16*)take(H0);  u16* c0 = (u16*)take(H0);
  u16* WallT = (u16*)take((size_t)512 * 128 * 2);
  u16* BihT = (u16*)take((size_t)128 * 128 * 2);
  u16* BuhT = (u16*)take((size_t)128 * 128 * 2);
  u16* BohT = (u16*)take((size_t)128 * 128 * 2);
  u16* BfhT = (u16*)take((size_t)128 * 128 * 2);
  float* bsum = (float*)take(512 * 4);

  // ---- prep ----
  build_wallT<<<256, 256, 0, stream>>>(W_ix, W_ux, W_ox, W_fx, WallT);
  build_bsum<<<2, 256, 0, stream>>>(b_ix, b_ih, b_ux, b_uh, b_ox, b_oh, b_fx, b_fh, bsum);
  build_bt128<<<64, 256, 0, stream>>>(W_ih, BihT);
  build_bt128<<<64, 256, 0, stream>>>(W_uh, BuhT);
  build_bt128<<<64, 256, 0, stream>>>(W_oh, BohT);
  build_bt128<<<64, 256, 0, stream>>>(W_fh, BfhT);
  proj_e<<<391, 256, 0, stream>>>(emb, WallT, bsum, Ep);
  leaf_hc<<<12500, 256, 0, stream>>>(Ep, Hl, Cl);

  const long LOFF[6] = {0, 4096, 20480, 86016, 217088, 479232};

  // L3 (131072 parents) with L4 computed in-kernel (h-side MFMA + prefetched Ep x-side)
  k_l3fused<<<4096, 256, 0, stream>>>(sen, Ep, Hl, Cl,
      BfhT, BihT, BuhT, BohT, c3, h3, LOFF[3], LOFF[4], LOFF[5]);
  // L2 (65536, ratio 2)
  k_level<1><<<1024, 256, 0, stream>>>(sen, Ep, h3, c3,
      BfhT, BihT, BuhT, BohT, c2, h2, LOFF[2]);
  // L1 (16384, ratio 4)
  k_level<2><<<512, 256, 0, stream>>>(sen, Ep, h2, c2,
      BfhT, BihT, BuhT, BohT, c1, h1, LOFF[1]);
  // L0 (4096, ratio 4)
  k_level<2><<<128, 256, 0, stream>>>(sen, Ep, h1, c1,
      BfhT, BihT, BuhT, BohT, c0, h0, LOFF[0]);

  out_proj<<<64, 256, 0, stream>>>(h0, W_out, b_out, out);
}

// Round 10
// 483.834 us; speedup vs baseline: 1.4494x; 1.0215x over previous
//
#include <hip/hip_runtime.h>
#include <hip/hip_bf16.h>
#include <cstdio>

typedef unsigned short u16;
typedef __bf16 bf16x8 __attribute__((ext_vector_type(8)));
typedef float  floatx4 __attribute__((ext_vector_type(4)));

// ---------- scalar helpers ----------
__device__ __forceinline__ float bf2f(u16 u) {
  union { unsigned int i; float f; } v; v.i = ((unsigned int)u) << 16; return v.f;
}
__device__ __forceinline__ u16 f2bf(float f) {
  union { float f; unsigned int i; } v; v.f = f;
  unsigned int x = v.i;
  return (u16)((x + 0x7fffu + ((x >> 16) & 1u)) >> 16);   // RNE
}
__device__ __forceinline__ unsigned int f2bf_pk(float a, float b) {   // [lo=a, hi=b]
  __hip_bfloat162 h = __float22bfloat162_rn(make_float2(a, b));
  union { __hip_bfloat162 h; unsigned int u; } v; v.h = h; return v.u;
}
// fast gates: v_rcp (~1 ulp) + native exp — no IEEE div
__device__ __forceinline__ float sigmoidf_(float x) {
  return __builtin_amdgcn_rcpf(1.f + __expf(-x));
}
__device__ __forceinline__ float tanhf_(float x) {
  return fmaf(-2.f, __builtin_amdgcn_rcpf(1.f + __expf(2.f * x)), 1.f);
}

// LDS swizzle, 128-elem rows, 16B chunks: chunk' = chunk ^ (row&15)
__device__ __forceinline__ int swz128(int row, int c16) {
  return row * 128 + ((c16 ^ (row & 15)) << 3);
}
// element-level access into swizzled rows
__device__ __forceinline__ int swze(int row, int col) {
  return row * 128 + (((((col >> 3)) ^ (row & 15)) << 3) | (col & 7));
}

// ============ proj_e: Ep[v][col][4] = {i,u,o,f} pre-acts + biases (gate-interleaved) ============
__global__ __launch_bounds__(256, 2) void proj_e(
    const float* __restrict__ emb, const u16* __restrict__ WT,
    const float* __restrict__ bsum, u16* __restrict__ Ep)
{
  __shared__ __align__(16) u16 ldsA[128 * 128];
  const int tid = threadIdx.x;
  const long m0 = (long)blockIdx.x * 128;
  {
    const int r = tid >> 1, half = tid & 1;
    long row = m0 + r; if (row > 49999) row = 49999;
    const float* src = emb + row * 128 + half * 64;
#pragma unroll
    for (int i = 0; i < 8; i++) {
      float4 v0 = *reinterpret_cast<const float4*>(src + i * 8);
      float4 v1 = *reinterpret_cast<const float4*>(src + i * 8 + 4);
      unsigned int ov[4] = { f2bf_pk(v0.x, v0.y), f2bf_pk(v0.z, v0.w),
                             f2bf_pk(v1.x, v1.y), f2bf_pk(v1.z, v1.w) };
      *reinterpret_cast<uint4*>(&ldsA[swz128(r, half * 8 + i)]) =
          *reinterpret_cast<const uint4*>(ov);
    }
  }
  __syncthreads();
  const int lane = tid & 63, w = tid >> 6, l16 = lane & 15, quad = lane >> 4;
#pragma unroll
  for (int half = 0; half < 2; half++) {
    const int col = w * 32 + half * 16 + l16;
    bf16x8 bI[4], bU[4], bO[4], bF[4];
#pragma unroll
    for (int ks = 0; ks < 4; ks++) {
      const size_t o_ = ks * 32 + quad * 8;
      bI[ks] = *reinterpret_cast<const bf16x8*>(WT + (size_t)(0   + col) * 128 + o_);
      bU[ks] = *reinterpret_cast<const bf16x8*>(WT + (size_t)(128 + col) * 128 + o_);
      bO[ks] = *reinterpret_cast<const bf16x8*>(WT + (size_t)(256 + col) * 128 + o_);
      bF[ks] = *reinterpret_cast<const bf16x8*>(WT + (size_t)(384 + col) * 128 + o_);
    }
    const float bi = bsum[col], bu = bsum[128 + col], bo = bsum[256 + col], bf = bsum[384 + col];
#pragma unroll
    for (int i = 0; i < 8; i++) {
      floatx4 aI = {0.f,0.f,0.f,0.f}, aU = {0.f,0.f,0.f,0.f};
      floatx4 aO = {0.f,0.f,0.f,0.f}, aF = {0.f,0.f,0.f,0.f};
#pragma unroll
      for (int ks = 0; ks < 4; ks++) {
        bf16x8 a = *reinterpret_cast<const bf16x8*>(&ldsA[swz128(i * 16 + l16, ks * 4 + quad)]);
        aI = __builtin_amdgcn_mfma_f32_16x16x32_bf16(a, bI[ks], aI, 0, 0, 0);
        aU = __builtin_amdgcn_mfma_f32_16x16x32_bf16(a, bU[ks], aU, 0, 0, 0);
        aO = __builtin_amdgcn_mfma_f32_16x16x32_bf16(a, bO[ks], aO, 0, 0, 0);
        aF = __builtin_amdgcn_mfma_f32_16x16x32_bf16(a, bF[ks], aF, 0, 0, 0);
      }
#pragma unroll
      for (int r2 = 0; r2 < 4; r2++) {
        const long row = m0 + i * 16 + quad * 4 + r2;
        if (row < 50000) {
          u16 ov[4] = { f2bf(aI[r2] + bi), f2bf(aU[r2] + bu),
                        f2bf(aO[r2] + bo), f2bf(aF[r2] + bf) };
          *reinterpret_cast<ushort4*>(Ep + row * 512 + col * 4) =
              *reinterpret_cast<const ushort4*>(ov);
        }
      }
    }
  }
}

// ============ leaf_hc: vocab-level leaf activations Hl[v][128], Cl[v][128] ============
__global__ void leaf_hc(const u16* __restrict__ Ep,
                        u16* __restrict__ Hl, u16* __restrict__ Cl)
{
  const int tid = threadIdx.x;
  const int r = tid >> 6, c2 = tid & 63;           // 4 vocab rows/block, 2 cols/thread
  const size_t v = (size_t)blockIdx.x * 4 + r;     // grid = 12500 -> covers 50000 exactly
  uint4 g = *reinterpret_cast<const uint4*>(Ep + v * 512 + (size_t)c2 * 8);
  const u16* p = reinterpret_cast<const u16*>(&g); // {i,u,o,f} x 2 cols
  float c0 = sigmoidf_(bf2f(p[0])) * tanhf_(bf2f(p[1]));
  float c1 = sigmoidf_(bf2f(p[4])) * tanhf_(bf2f(p[5]));
  float h0 = sigmoidf_(bf2f(p[2])) * tanhf_(c0);
  float h1 = sigmoidf_(bf2f(p[6])) * tanhf_(c1);
  *reinterpret_cast<unsigned int*>(Hl + v * 128 + c2 * 2) = f2bf_pk(h0, h1);
  *reinterpret_cast<unsigned int*>(Cl + v * 128 + c2 * 2) = f2bf_pk(c0, c1);
}

// ============ k_l3fused v5: v4 pipeline with NAMED-REGISTER prefetch (no scratch) ============
// R9 evidence: array-based prefetch spilled (VGPR 120->84, WRITE 71->168 MB scratch traffic)
// yet still won 24us -> the latency theory holds; the arrays must live in registers.
// v5: 1-deep software pipeline with named SSA vars (e0..e3 / n0..n3, g0,g1 / m0,m1) and
// literal-index epilogue macros (no runtime vector indexing). launch_bounds(256,2):
// full VGPR budget; LDS (48.6KB) caps occupancy at 3 blocks/CU regardless.
__global__ __launch_bounds__(256, 2) void k_l3fused(
    const int* __restrict__ sen, const u16* __restrict__ Ep,
    const u16* __restrict__ Hl, const u16* __restrict__ Cl,
    const u16* __restrict__ BfT, const u16* __restrict__ BihT,
    const u16* __restrict__ BuhT, const u16* __restrict__ BohT,
    u16* __restrict__ c_out, u16* __restrict__ h_out,
    long o0, long o1, long o2)
{
  constexpr int PM = 32, CM = 64, NCI = 4, RT = 2;
  __shared__ __align__(16) u16 ldsH[CM * 128];   // leaf h (swz) 16 KB
  __shared__ __align__(16) u16 ldsC[CM * 128];   // leaf c -> L4 c in place (swz) 16 KB
  __shared__ __align__(16) u16 ldsA[CM * 128];   // L4 h (swz) 16 KB
  __shared__ int sidC[CM];                       // L4-node vocab ids
  __shared__ int sidP[PM];                       // L3-parent vocab ids

  const int tid = threadIdx.x;
  const long p0 = (long)blockIdx.x * PM;
  const long cb = (long)blockIdx.x * CM;

  // ---- phase 0: stage Hl/Cl (2 threads/row/table, 8 uint4 each -> high MLP) ----
  {
    const int r = (tid & 127) >> 1, half = tid & 1;
    const size_t vc = (size_t)sen[o2 + cb + r];   // leaf child's vocab id
    if (tid < 128) {
      const u16* hs = Hl + vc * 128;
#pragma unroll
      for (int ii = 0; ii < 8; ii++) {
        const int c16 = half * 8 + ii;
        *reinterpret_cast<uint4*>(&ldsH[swz128(r, c16)]) =
            *reinterpret_cast<const uint4*>(hs + c16 * 8);
      }
    } else {
      const u16* cs = Cl + vc * 128;
#pragma unroll
      for (int ii = 0; ii < 8; ii++) {
        const int c16 = half * 8 + ii;
        *reinterpret_cast<uint4*>(&ldsC[swz128(r, c16)]) =
            *reinterpret_cast<const uint4*>(cs + c16 * 8);
      }
    }
    if (tid < CM) sidC[tid] = sen[o1 + cb + tid];
    if (tid < PM) sidP[tid] = sen[o0 + p0 + tid];
  }
  __syncthreads();

  const int lane = tid & 63, w = tid >> 6, l16 = lane & 15, quad = lane >> 4;

  // ---- phase 1: L4 = act(Hl@W_*h + Ep[vp]) ; c4/h4 into LDS ----
#define LDE(I,R2) (*reinterpret_cast<const ushort4*>( \
    Ep + (size_t)sidC[(I) * 16 + quad * 4 + (R2)] * 512 + col * 4))
#define EPI1(R2, E) { \
    const int row = rbase + (R2); \
    const float iv = sigmoidf_(aI[R2] + bf2f((E).x)); \
    const float uv = tanhf_   (aU[R2] + bf2f((E).y)); \
    const float ov = sigmoidf_(aO[R2] + bf2f((E).z)); \
    const float fv = sigmoidf_(aF[R2] + bf2f((E).w)); \
    const int sl = swze(row, col); \
    const float c4 = fmaf(iv, uv, fv * bf2f(ldsC[sl])); \
    const float h4 = ov * tanhf_(c4); \
    ldsC[sl] = f2bf(c4); \
    ldsA[sl] = f2bf(h4); \
  }
#pragma unroll
  for (int gl = 0; gl < 2; gl++) {
    const int col = w * 32 + gl * 16 + l16;
    // prime the pipeline: i=0's four x-side preact reads
    ushort4 e0 = LDE(0, 0), e1 = LDE(0, 1), e2 = LDE(0, 2), e3 = LDE(0, 3);
    bf16x8 hI[4], hU[4], hO[4], hF[4];
#pragma unroll
    for (int ks = 0; ks < 4; ks++) {
      const size_t ho = (size_t)col * 128 + ks * 32 + quad * 8;
      hI[ks] = *reinterpret_cast<const bf16x8*>(BihT + ho);
      hU[ks] = *reinterpret_cast<const bf16x8*>(BuhT + ho);
      hO[ks] = *reinterpret_cast<const bf16x8*>(BohT + ho);
      hF[ks] = *reinterpret_cast<const bf16x8*>(BfT  + ho);
    }
#pragma unroll
    for (int i = 0; i < NCI; i++) {
      ushort4 n0 = e0, n1 = e1, n2 = e2, n3 = e3;
      if (i + 1 < NCI) {              // prefetch next i (in flight across the MFMAs)
        n0 = LDE(i + 1, 0); n1 = LDE(i + 1, 1);
        n2 = LDE(i + 1, 2); n3 = LDE(i + 1, 3);
      }
      floatx4 aI = {0.f,0.f,0.f,0.f}, aU = {0.f,0.f,0.f,0.f};
      floatx4 aO = {0.f,0.f,0.f,0.f}, aF = {0.f,0.f,0.f,0.f};
#pragma unroll
      for (int ks = 0; ks < 4; ks++) {
        bf16x8 ah = *reinterpret_cast<const bf16x8*>(&ldsH[swz128(i * 16 + l16, ks * 4 + quad)]);
        aI = __builtin_amdgcn_mfma_f32_16x16x32_bf16(ah, hI[ks], aI, 0, 0, 0);
        aU = __builtin_amdgcn_mfma_f32_16x16x32_bf16(ah, hU[ks], aU, 0, 0, 0);
        aO = __builtin_amdgcn_mfma_f32_16x16x32_bf16(ah, hO[ks], aO, 0, 0, 0);
        aF = __builtin_amdgcn_mfma_f32_16x16x32_bf16(ah, hF[ks], aF, 0, 0, 0);
      }
      const int rbase = i * 16 + quad * 4;
      EPI1(0, e0) EPI1(1, e1) EPI1(2, e2) EPI1(3, e3)
      e0 = n0; e1 = n1; e2 = n2; e3 = n3;
    }
  }
#undef LDE
#undef EPI1
  __syncthreads();

  // ---- phase 2: L3 tree-LSTM step ----
#define LDG(I,T) (*reinterpret_cast<const ushort4*>( \
    Ep + (size_t)sidP[(((I) * 16 + quad * 4) >> 1) + (T)] * 512 + col * 4))
#define EPI2(T, G) { \
    const int p = (rbase >> 1) + (T); \
    const float epf = bf2f((G).w); \
    float fsum = 0.f, isum = 0.f, usum = 0.f, osum = 0.f; \
    _Pragma("unroll") \
    for (int r2 = (T) * RT; r2 < (T) * RT + RT; r2++) { \
      const int row = rbase + r2; \
      const float cch = bf2f(ldsC[swze(row, col)]); \
      fsum += sigmoidf_(aF[r2] + epf) * cch; \
      isum += aI[r2]; usum += aU[r2]; osum += aO[r2]; \
    } \
    const float c = sigmoidf_(isum + bf2f((G).x)) * tanhf_(usum + bf2f((G).y)) + fsum; \
    const float h = sigmoidf_(osum + bf2f((G).z)) * tanhf_(c); \
    c_out[(p0 + p) * 128 + col] = f2bf(c); \
    h_out[(p0 + p) * 128 + col] = f2bf(h); \
  }
#pragma unroll
  for (int gl = 0; gl < 2; gl++) {
    const int col = w * 32 + gl * 16 + l16;
    ushort4 g0 = LDG(0, 0), g1 = LDG(0, 1);
    bf16x8 bF[4], bI[4], bU[4], bO[4];
#pragma unroll
    for (int ks = 0; ks < 4; ks++) {
      const size_t bo_ = (size_t)col * 128 + ks * 32 + quad * 8;
      bF[ks] = *reinterpret_cast<const bf16x8*>(BfT + bo_);
      bI[ks] = *reinterpret_cast<const bf16x8*>(BihT + bo_);
      bU[ks] = *reinterpret_cast<const bf16x8*>(BuhT + bo_);
      bO[ks] = *reinterpret_cast<const bf16x8*>(BohT + bo_);
    }
#pragma unroll
    for (int i = 0; i < NCI; i++) {
      ushort4 m0 = g0, m1 = g1;
      if (i + 1 < NCI) { m0 = LDG(i + 1, 0); m1 = LDG(i + 1, 1); }
      floatx4 aF = {0.f,0.f,0.f,0.f}, aI = {0.f,0.f,0.f,0.f};
      floatx4 aU = {0.f,0.f,0.f,0.f}, aO = {0.f,0.f,0.f,0.f};
#pragma unroll
      for (int ks = 0; ks < 4; ks++) {
        bf16x8 a = *reinterpret_cast<const bf16x8*>(&ldsA[swz128(i * 16 + l16, ks * 4 + quad)]);
        aF = __builtin_amdgcn_mfma_f32_16x16x32_bf16(a, bF[ks], aF, 0, 0, 0);
        aI = __builtin_amdgcn_mfma_f32_16x16x32_bf16(a, bI[ks], aI, 0, 0, 0);
        aU = __builtin_amdgcn_mfma_f32_16x16x32_bf16(a, bU[ks], aU, 0, 0, 0);
        aO = __builtin_amdgcn_mfma_f32_16x16x32_bf16(a, bO[ks], aO, 0, 0, 0);
      }
      const int rbase = i * 16 + quad * 4;
      EPI2(0, g0) EPI2(1, g1)
      g0 = m0; g1 = m1;
    }
  }
#undef LDG
#undef EPI2
}

// ============ k_level: per-i-tile fused f/i/u/o (inner levels, computed children) ============
// Epilogue operands (g4 from Ep, cch from c_prev) prefetched at the top of each i-iter
// so the loads overlap the 16 MFMAs instead of stalling the epilogue.
template<int LR>
__global__ __launch_bounds__(256, 2) void k_level(
    const int* __restrict__ sen, const u16* __restrict__ Ep,
    const u16* __restrict__ h_prev, const u16* __restrict__ c_prev,
    const u16* __restrict__ BfT, const u16* __restrict__ BihT,
    const u16* __restrict__ BuhT, const u16* __restrict__ BohT,
    u16* __restrict__ c_out, u16* __restrict__ h_out,
    long o0)
{
  constexpr int PM  = (LR == 2) ? 32 : 64;
  constexpr int CM  = PM << LR;
  constexpr int NCI = CM / 16;
  constexpr int RT  = 1 << LR;
  constexpr int RTI = 4 >> LR;         // parents per 4-row quad block
  constexpr int TPR = 256 / CM;        // staging threads per child row
  __shared__ __align__(16) u16 ldsA[CM * 128];   // child h (swz)
  __shared__ int sidP[PM];

  const int tid = threadIdx.x;
  const long p0 = (long)blockIdx.x * PM;
  const long cb = (long)blockIdx.x * CM;

  // ---- stage children ----
  {
    const int r = tid / TPR, q = tid % TPR;
    constexpr int CH = 16 / TPR;
    const u16* src = h_prev + (cb + r) * 128;
#pragma unroll
    for (int ii = 0; ii < CH; ii++) {
      const int c16 = q * CH + ii;
      *reinterpret_cast<uint4*>(&ldsA[swz128(r, c16)]) =
          *reinterpret_cast<const uint4*>(src + c16 * 8);
    }
    if (tid < PM) sidP[tid] = sen[o0 + p0 + tid];
  }
  __syncthreads();

  const int lane = tid & 63, w = tid >> 6, l16 = lane & 15, quad = lane >> 4;

#pragma unroll
  for (int gl = 0; gl < 2; gl++) {
    const int col = w * 32 + gl * 16 + l16;
    bf16x8 bF[4], bI[4], bU[4], bO[4];
#pragma unroll
    for (int ks = 0; ks < 4; ks++) {
      const size_t bo_ = (size_t)col * 128 + ks * 32 + quad * 8;
      bF[ks] = *reinterpret_cast<const bf16x8*>(BfT + bo_);
      bI[ks] = *reinterpret_cast<const bf16x8*>(BihT + bo_);
      bU[ks] = *reinterpret_cast<const bf16x8*>(BuhT + bo_);
      bO[ks] = *reinterpret_cast<const bf16x8*>(BohT + bo_);
    }
#pragma unroll
    for (int i = 0; i < NCI; i++) {
      const int rbase = i * 16 + quad * 4;
      // prefetch epilogue operands before the MFMA chain
      ushort4 g4p[RTI];
      u16 cch16[RTI][RT];
#pragma unroll
      for (int t = 0; t < RTI; t++) {
        g4p[t] = *reinterpret_cast<const ushort4*>(
            Ep + (size_t)sidP[(rbase >> LR) + t] * 512 + col * 4);
#pragma unroll
        for (int r2 = 0; r2 < RT; r2++)
          cch16[t][r2] = c_prev[(cb + rbase + t * RT + r2) * 128 + col];
      }
      floatx4 aF = {0.f,0.f,0.f,0.f}, aI = {0.f,0.f,0.f,0.f};
      floatx4 aU = {0.f,0.f,0.f,0.f}, aO = {0.f,0.f,0.f,0.f};
#pragma unroll
      for (int ks = 0; ks < 4; ks++) {
        bf16x8 a = *reinterpret_cast<const bf16x8*>(&ldsA[swz128(i * 16 + l16, ks * 4 + quad)]);
        aF = __builtin_amdgcn_mfma_f32_16x16x32_bf16(a, bF[ks], aF, 0, 0, 0);
        aI = __builtin_amdgcn_mfma_f32_16x16x32_bf16(a, bI[ks], aI, 0, 0, 0);
        aU = __builtin_amdgcn_mfma_f32_16x16x32_bf16(a, bU[ks], aU, 0, 0, 0);
        aO = __builtin_amdgcn_mfma_f32_16x16x32_bf16(a, bO[ks], aO, 0, 0, 0);
      }
#pragma unroll
      for (int t = 0; t < RTI; t++) {
        const int p = (rbase >> LR) + t;
        const ushort4 g4 = g4p[t];
        const float epf = bf2f(g4.w);
        float fsum = 0.f, isum = 0.f, usum = 0.f, osum = 0.f;
#pragma unroll
        for (int r2 = t * RT; r2 < t * RT + RT; r2++) {
          const float cch = bf2f(cch16[t][r2 - t * RT]);
          fsum += sigmoidf_(aF[r2] + epf) * cch;
          isum += aI[r2]; usum += aU[r2]; osum += aO[r2];
        }
        const float c = sigmoidf_(isum + bf2f(g4.x)) * tanhf_(usum + bf2f(g4.y)) + fsum;
        const float h = sigmoidf_(osum + bf2f(g4.z)) * tanhf_(c);
        c_out[(p0 + p) * 128 + col] = f2bf(c);
        h_out[(p0 + p) * 128 + col] = f2bf(h);
      }
    }
  }
}

// ---------- weight/bias prep ----------
__global__ void build_wallT(const float* __restrict__ Wix, const float* __restrict__ Wux,
                            const float* __restrict__ Wox, const float* __restrict__ Wfx,
                            u16* __restrict__ WT)
{
  int idx = blockIdx.x * 256 + threadIdx.x;   // 512*128
  int n = idx >> 7, k = idx & 127;
  int g = n >> 7, j = n & 127;
  const float* W = (g == 0) ? Wix : (g == 1) ? Wux : (g == 2) ? Wox : Wfx;
  WT[idx] = f2bf(W[k * 128 + j]);
}

__global__ void build_bsum(const float* __restrict__ b_ix, const float* __restrict__ b_ih,
                           const float* __restrict__ b_ux, const float* __restrict__ b_uh,
                           const float* __restrict__ b_ox, const float* __restrict__ b_oh,
                           const float* __restrict__ b_fx, const float* __restrict__ b_fh,
                           float* __restrict__ bsum)
{
  int n = blockIdx.x * 256 + threadIdx.x;   // 512
  int g = n >> 7, j = n & 127;
  float v = (g == 0) ? b_ix[j] + b_ih[j] : (g == 1) ? b_ux[j] + b_uh[j]
          : (g == 2) ? b_ox[j] + b_oh[j] : b_fx[j] + b_fh[j];
  bsum[n] = v;
}

__global__ void build_bt128(const float* __restrict__ W, u16* __restrict__ BT) {
  int idx = blockIdx.x * 256 + threadIdx.x;   // 128*128
  int n = idx >> 7, k = idx & 127;
  BT[idx] = f2bf(W[k * 128 + n]);
}

// ---------- output projection (4096 x 4, tiny) ----------
__global__ void out_proj(const u16* __restrict__ h_root, const float* __restrict__ W_out,
                         const float* __restrict__ b_out, float* __restrict__ out)
{
  int idx = blockIdx.x * 256 + threadIdx.x;   // 4096*4
  int n = idx >> 2, cls = idx & 3;
  float s = b_out[cls];
  for (int k = 0; k < 128; k++)
    s += bf2f(h_root[(long)n * 128 + k]) * W_out[k * 4 + cls];
  out[idx] = s;
}

extern "C" void kernel_launch(void* const* d_in, const int* in_sizes, int n_in,
                              void* d_out, int out_size, void* d_ws, size_t ws_size,
                              hipStream_t stream)
{
  const int*   sen  = (const int*)d_in[0];
  const float* emb  = (const float*)d_in[1];
  const float* W_ix = (const float*)d_in[2];  const float* b_ix = (const float*)d_in[3];
  const float* W_ih = (const float*)d_in[4];  const float* b_ih = (const float*)d_in[5];
  const float* W_fx = (const float*)d_in[6];  const float* b_fx = (const float*)d_in[7];
  const float* W_fh = (const float*)d_in[8];  const float* b_fh = (const float*)d_in[9];
  const float* W_ox = (const float*)d_in[10]; const float* b_ox = (const float*)d_in[11];
  const float* W_oh = (const float*)d_in[12]; const float* b_oh = (const float*)d_in[13];
  const float* W_ux = (const float*)d_in[14]; const float* b_ux = (const float*)d_in[15];
  const float* W_uh = (const float*)d_in[16]; const float* b_uh = (const float*)d_in[17];
  const float* W_out= (const float*)d_in[18]; const float* b_out= (const float*)d_in[19];
  float* out = (float*)d_out;

  // ---- workspace ----
  const size_t EPB = (size_t)50000 * 512 * 2;       // Ep (51.2 MB)
  const size_t TBB = (size_t)50000 * 128 * 2;       // Hl / Cl (12.8 MB each)
  const size_t H3  = (size_t)131072 * 128 * 2;      // 33.55 MB each
  const size_t H2  = (size_t)65536  * 128 * 2;
  const size_t H1  = (size_t)16384  * 128 * 2;
  const size_t H0  = (size_t)4096   * 128 * 2;
  const size_t need = EPB + 2 * TBB + 2 * (H3 + H2 + H1 + H0)
                    + (size_t)512 * 128 * 2 + 4 * (size_t)128 * 128 * 2 + 512 * 4 + 8192;
  fprintf(stderr, "[tree_lstm] ws_size=%zu need=%zu\n", ws_size, need);
  if (ws_size < need) {
    fprintf(stderr, "[tree_lstm] INSUFFICIENT WORKSPACE — skipping launch\n");
    return;
  }
  char* ws = (char*)d_ws;
  size_t off = 0;
  auto take = [&](size_t bytes) { char* p = ws + off; off += (bytes + 255) & ~(size_t)255; return p; };
  u16* Ep = (u16*)take(EPB);
  u16* Hl = (u16*)take(TBB);
  u16* Cl = (u16*)take(TBB);
  u16* h3 = (u16*)take(H3);  u16* c3 = (u16*)take(H3);
  u16* h2 = (u16*)take(H2);  u16* c2 = (u16*)take(H2);
  u16* h1 = (u16*)take(H1);  u16* c1 = (u16*)take(H1);
  u16* h0 = (u16*)take(H0);  u16* c0 = (u16*)take(H0);
  u16* WallT = (u16*)take((size_t)512 * 128 * 2);
  u16* BihT = (u16*)take((size_t)128 * 128 * 2);
  u16* BuhT = (u16*)take((size_t)128 * 128 * 2);
  u16* BohT = (u16*)take((size_t)128 * 128 * 2);
  u16* BfhT = (u16*)take((size_t)128 * 128 * 2);
  float* bsum = (float*)take(512 * 4);

  // ---- prep ----
  build_wallT<<<256, 256, 0, stream>>>(W_ix, W_ux, W_ox, W_fx, WallT);
  build_bsum<<<2, 256, 0, stream>>>(b_ix, b_ih, b_ux, b_uh, b_ox, b_oh, b_fx, b_fh, bsum);
  build_bt128<<<64, 256, 0, stream>>>(W_ih, BihT);
  build_bt128<<<64, 256, 0, stream>>>(W_uh, BuhT);
  build_bt128<<<64, 256, 0, stream>>>(W_oh, BohT);
  build_bt128<<<64, 256, 0, stream>>>(W_fh, BfhT);
  proj_e<<<391, 256, 0, stream>>>(emb, WallT, bsum, Ep);
  leaf_hc<<<12500, 256, 0, stream>>>(Ep, Hl, Cl);

  const long LOFF[6] = {0, 4096, 20480, 86016, 217088, 479232};

  // L3 (131072 parents) with L4 computed in-kernel (h-side MFMA + pipelined Ep x-side)
  k_l3fused<<<4096, 256, 0, stream>>>(sen, Ep, Hl, Cl,
      BfhT, BihT, BuhT, BohT, c3, h3, LOFF[3], LOFF[4], LOFF[5]);
  // L2 (65536, ratio 2)
  k_level<1><<<1024, 256, 0, stream>>>(sen, Ep, h3, c3,
      BfhT, BihT, BuhT, BohT, c2, h2, LOFF[2]);
  // L1 (16384, ratio 4)
  k_level<2><<<512, 256, 0, stream>>>(sen, Ep, h2, c2,
      BfhT, BihT, BuhT, BohT, c1, h1, LOFF[1]);
  // L0 (4096, ratio 4)
  k_level<2><<<128, 256, 0, stream>>>(sen, Ep, h1, c1,
      BfhT, BihT, BuhT, BohT, c0, h0, LOFF[0]);

  out_proj<<<64, 256, 0, stream>>>(h0, W_out, b_out, out);
}